// Round 5
// baseline (188.105 us; speedup 1.0000x reference)
//
#include <hip/hip_runtime.h>
#include <hip/hip_bf16.h>
#include <cstdint>
#include <cstddef>

typedef float  f32x4  __attribute__((ext_vector_type(4)));
typedef __bf16 bf16x8 __attribute__((ext_vector_type(8)));
typedef __bf16 bf16x4 __attribute__((ext_vector_type(4)));

#define HIDDEN 1024
#define SEQ    2048
#define BATCH  2
#define NQKV   3072
#define MTOT   4096

__device__ __forceinline__ __bf16 f2bf(float f) {
  unsigned u = __builtin_bit_cast(unsigned, f);
  u += 0x7FFFu + ((u >> 16) & 1u);          // round-to-nearest-even
  unsigned short s = (unsigned short)(u >> 16);
  return __builtin_bit_cast(__bf16, s);
}

// pack two f32 -> bf16x2 (round-half-up) in 3 VALU: 2 adds + 1 v_perm_b32
__device__ __forceinline__ unsigned pk2(float a, float b) {
  unsigned ua = __builtin_bit_cast(unsigned, a) + 0x8000u;
  unsigned ub = __builtin_bit_cast(unsigned, b) + 0x8000u;
  return __builtin_amdgcn_perm(ub, ua, 0x07060302u);  // {hi16(ub), hi16(ua)}
}

__device__ __forceinline__ float fexp2(float x) {
#if __has_builtin(__builtin_amdgcn_exp2f)
  return __builtin_amdgcn_exp2f(x);   // bare v_exp_f32
#else
  return exp2f(x);
#endif
}

__device__ __forceinline__ void async16(const void* g, void* l) {
  __builtin_amdgcn_global_load_lds((__attribute__((address_space(1))) void*)(g),
                                   (__attribute__((address_space(3))) void*)(l),
                                   16, 0, 0);
}

// ---------------- prep: x->bf16 convert + both weight transposes (one launch) ----
__global__ __launch_bounds__(256) void k_prep(const float* __restrict__ x,
                                              __bf16* __restrict__ xb,
                                              const float* __restrict__ qkv_w,
                                              __bf16* __restrict__ wqkT,
                                              const float* __restrict__ out_w,
                                              __bf16* __restrict__ woT) {
  __shared__ float tile[64][65];
  const int bid = blockIdx.x, t = threadIdx.x;
  if (bid < 4096) {
    int i = bid * 256 + t;
    float4 v = ((const float4*)x)[i];
    bf16x4 o;
    o[0] = f2bf(v.x); o[1] = f2bf(v.y); o[2] = f2bf(v.z); o[3] = f2bf(v.w);
    ((bf16x4*)xb)[i] = o;
    return;
  }
  const float* W; __bf16* WT; int N, bx, by;
  if (bid < 4864) { int g = bid - 4096; W = qkv_w; WT = wqkT; N = NQKV;  bx = g % 48; by = g / 48; }
  else            { int g = bid - 4864; W = out_w; WT = woT;  N = HIDDEN; bx = g % 16; by = g / 16; }
  const int K = HIDDEN;
  int tx = t & 63, ty = t >> 6;
  int n0 = bx * 64, k0 = by * 64;
#pragma unroll
  for (int r = 0; r < 16; r++) {
    int row = r * 4 + ty;
    tile[row][tx] = W[(size_t)(k0 + row) * N + n0 + tx];
  }
  __syncthreads();
#pragma unroll
  for (int i2 = 0; i2 < 2; i2++) {
    int cc = i2 * 256 + t;
    int n = cc >> 3, ch = cc & 7;
    bf16x8 o;
#pragma unroll
    for (int j = 0; j < 8; j++) o[j] = f2bf(tile[ch * 8 + j][n]);
    *(bf16x8*)(WT + (size_t)(n0 + n) * K + k0 + ch * 8) = o;
  }
}

// ---------------- QKV GEMM: 256x256 tile, BK=32, 8 waves, 4-deep counted ring ----
// R5: the 128-wide tile's 2750 cyc/K-step had no pipe >30% busy -> the critical
// path was stage->wait->barrier itself (m233's 2-phase stall). Fix per T3/T4
// regime gate: 256x256 tile (2x FLOP per staged byte: 32 MFMA/wave/step vs 16),
// 4-deep LDS ring (4x16KB A + 4x16KB B = 128 KB), ONE barrier per K-step with
// counted s_waitcnt vmcnt(8) (2 stages in flight, never drains mid-loop), stage
// issued 3 steps ahead (~3 compute phases of cover vs <1 before).
// Ring hazards: at top of step j, all waves' reads of buf[(j-1)&3] retired
// (register deps before their MFMAs, then the barrier) -> safe to stage tile
// j+3 into that same buffer right after the barrier. vmcnt(8) at top of j
// drains stage(j) (12 outstanding -> 8). Tail: rem==1 -> vmcnt(4), rem==0 -> 0.
// Same BK=32 XOR swizzle as the proven 128-tile kernel (bank conflicts = 0).
// Grid 16x12=192, XCD-bijective 3bx x 8by rectangles (nwg%8==0).
// VFUSE epilogue: Q cols pre-scaled by CE, V cols -> vt permuted (16-col groups
// never straddle Q/K/V since all bases are multiples of 16).
__global__ __launch_bounds__(512, 2) void k_qkv(const __bf16* __restrict__ A,
                                                const __bf16* __restrict__ BT,
                                                const float* __restrict__ bias,
                                                __bf16* __restrict__ Cout,
                                                __bf16* __restrict__ vt) {
  const int K = HIDDEN;
  __shared__ __align__(16) __bf16 As[4][256 * 32];   // 64 KB
  __shared__ __align__(16) __bf16 Bs[4][256 * 32];   // 64 KB
  const int t = threadIdx.x;
  const int lane = t & 63, wv = t >> 6;
  const int ln = lane & 15, quad = lane >> 4;
  const int sw8 = (quad ^ ((ln >> 1) & 3)) * 8;
  const int wm = (wv >> 2) * 128, wn = (wv & 3) * 64;   // wave = 128x64 of 256x256

  // XCD-bijective 2D chunk: xcd owns 3(bx) x 8(by) tile rectangle
  const int lin = blockIdx.x;
  const int xcd = lin & 7, wi = lin >> 3;          // wi in [0,24)
  const int bxi = (xcd & 3) * 3 + wi % 3;          // [0,12)
  const int byi = (xcd >> 2) * 8 + wi / 3;         // [0,16)
  const int m0 = byi * 256, n0 = bxi * 256;

  auto stage = [&](int k0, int p) {
    __bf16* Ad = As[p];
    __bf16* Bd = Bs[p];
#pragma unroll
    for (int i = 0; i < 2; i++) {          // A: 256x32 = 1024 chunks
      int tt = i * 512 + t;
      int row = tt >> 2, ch = tt & 3;
      int chs = ch ^ ((row >> 1) & 3);
      async16(A + (size_t)(m0 + row) * K + k0 + chs * 8, Ad + tt * 8);
    }
#pragma unroll
    for (int i = 0; i < 2; i++) {          // B: 256x32 = 1024 chunks
      int tt = i * 512 + t;
      int row = tt >> 2, ch = tt & 3;
      int chs = ch ^ ((row >> 1) & 3);
      async16(BT + (size_t)(n0 + row) * K + k0 + chs * 8, Bd + tt * 8);
    }
  };

  const f32x4 zero4 = {0.f, 0.f, 0.f, 0.f};
  f32x4 acc[8][4];
#pragma unroll
  for (int i = 0; i < 8; i++)
#pragma unroll
    for (int j = 0; j < 4; j++) acc[i][j] = zero4;

  stage(0, 0); stage(32, 1); stage(64, 2);   // depth-3 prologue (12 loads in flight)
  const int NIT = K / 32;                     // 32
  for (int j = 0; j < NIT; j++) {
    int rem = NIT - 1 - j;
    if (rem >= 2)      asm volatile("s_waitcnt vmcnt(8)\n\ts_barrier" ::: "memory");
    else if (rem == 1) asm volatile("s_waitcnt vmcnt(4)\n\ts_barrier" ::: "memory");
    else               asm volatile("s_waitcnt vmcnt(0)\n\ts_barrier" ::: "memory");
    if (j + 3 < NIT) stage((j + 3) * 32, (j + 3) & 3);   // into buffer read at j-1
    const __bf16* Asb = As[j & 3];
    const __bf16* Bsb = Bs[j & 3];
    bf16x8 af[8], bfr[4];
#pragma unroll
    for (int x = 0; x < 8; x++)
      af[x] = *(const bf16x8*)(Asb + (wm + x * 16 + ln) * 32 + sw8);
#pragma unroll
    for (int x = 0; x < 4; x++)
      bfr[x] = *(const bf16x8*)(Bsb + (wn + x * 16 + ln) * 32 + sw8);
#pragma unroll
    for (int mt = 0; mt < 8; mt++)
#pragma unroll
      for (int nt = 0; nt < 4; nt++)
        acc[mt][nt] = __builtin_amdgcn_mfma_f32_16x16x32_bf16(af[mt], bfr[nt], acc[mt][nt], 0, 0, 0);
  }

  const float CE = 0.125f * 1.44269504089f;
#pragma unroll
  for (int nt = 0; nt < 4; nt++) {
    int g = n0 + wn + nt * 16;      // lane-uniform 16-col group base
    int col = g + ln;
    float bv = bias[col];
    int off = g % 192;
    if (off < 128) {
      float scl = (off < 64) ? CE : 1.0f;    // pre-scale Q by CE
#pragma unroll
      for (int mt = 0; mt < 8; mt++) {
#pragma unroll
        for (int r = 0; r < 4; r++) {
          int row = m0 + wm + mt * 16 + quad * 4 + r;
          Cout[(size_t)row * NQKV + col] = f2bf((acc[mt][nt][r] + bv) * scl);
        }
      }
    } else {
      // V path: vt[bh][d][sblk*128 + p], p = permuted in-block position
      int hg = g / 192;
      int d  = off - 128 + ln;
#pragma unroll
      for (int mt = 0; mt < 8; mt++) {
        int rowb = m0 + wm + mt * 16;        // + quad*4 + r
        int bb = rowb >> 11;
        int s  = rowb & 2047;
        int sblk = s >> 7;
        int blk  = (s >> 4) & 7;             // (s%128)/16
        int p = (blk & 3) * 32 + quad * 8 + ((blk >> 2) << 2);
        uint2 o;
        o.x = pk2(acc[mt][nt][0] + bv, acc[mt][nt][1] + bv);
        o.y = pk2(acc[mt][nt][2] + bv, acc[mt][nt][3] + bv);
        *(uint2*)(vt + ((size_t)((bb * 16 + hg) * 64 + d)) * SEQ + sblk * 128 + p) = o;
      }
    }
  }
}

// ---------------- out GEMM: C[M][N] = A[M][K] * BT[N][K]^T + bias (f32 out) ----
// R3 form (2-buffer dbuf prefetch, drain-0): kept for N=1024 where 128x64 tiles
// give 512 blocks = 2/CU. R4's 3-buffer counted variant is the regression
// suspect and was reverted.
__global__ __launch_bounds__(256, 4) void k_gemm_out(const __bf16* __restrict__ A,
                                                     const __bf16* __restrict__ BT,
                                                     const float* __restrict__ bias,
                                                     float* __restrict__ Cout,
                                                     int M, int N, int K) {
  constexpr int TN = 64;
  __shared__ __align__(16) __bf16 As[2 * 128 * 32];
  __shared__ __align__(16) __bf16 Bs[2 * TN * 32];
  const int t = threadIdx.x;
  const int lane = t & 63, wv = t >> 6;
  const int ln = lane & 15, quad = lane >> 4;
  const int sw8 = (quad ^ ((ln >> 1) & 3)) * 8;
  const int wm = (wv & 1) * 64, wn = (wv >> 1) * (TN / 2);

  const int nbx = N / TN;                 // 16
  const int cx = nbx >> 1;                // 8
  const int lin = blockIdx.x;
  const int xcd = lin & 7, wi = lin >> 3;
  const int bxi = (xcd & 1) * cx + wi % cx;
  const int byi = (xcd >> 1) * 8 + wi / cx;
  const int m0 = byi * 128, n0 = bxi * TN;

  auto stage = [&](int k0, int p) {
    __bf16* Ad = As + p * (128 * 32);
    __bf16* Bd = Bs + p * (TN * 32);
#pragma unroll
    for (int i = 0; i < 2; i++) {
      int tt = i * 256 + t;
      int row = tt >> 2, ch = tt & 3;
      int chs = ch ^ ((row >> 1) & 3);
      async16(A + (size_t)(m0 + row) * K + k0 + chs * 8, Ad + tt * 8);
    }
    {
      int tt = t;
      int row = tt >> 2, ch = tt & 3;
      int chs = ch ^ ((row >> 1) & 3);
      async16(BT + (size_t)(n0 + row) * K + k0 + chs * 8, Bd + tt * 8);
    }
  };

  const f32x4 zero4 = {0.f, 0.f, 0.f, 0.f};
  f32x4 acc[4][2];
#pragma unroll
  for (int i = 0; i < 4; i++)
#pragma unroll
    for (int j = 0; j < 2; j++) acc[i][j] = zero4;

  stage(0, 0);
  const int NIT = K / 32;
  for (int it = 0; it < NIT; it++) {
    __syncthreads();
    if (it + 1 < NIT) stage((it + 1) * 32, (it + 1) & 1);
    const __bf16* Asb = As + (it & 1) * (128 * 32);
    const __bf16* Bsb = Bs + (it & 1) * (TN * 32);
    bf16x8 af[4], bfr[2];
#pragma unroll
    for (int x = 0; x < 4; x++)
      af[x] = *(const bf16x8*)(Asb + (wm + x * 16 + ln) * 32 + sw8);
#pragma unroll
    for (int x = 0; x < 2; x++)
      bfr[x] = *(const bf16x8*)(Bsb + (wn + x * 16 + ln) * 32 + sw8);
#pragma unroll
    for (int mt = 0; mt < 4; mt++)
#pragma unroll
      for (int nt = 0; nt < 2; nt++)
        acc[mt][nt] = __builtin_amdgcn_mfma_f32_16x16x32_bf16(af[mt], bfr[nt], acc[mt][nt], 0, 0, 0);
  }
#pragma unroll
  for (int nt = 0; nt < 2; nt++) {
    int col = n0 + wn + nt * 16 + ln;
    float bv = bias[col];
#pragma unroll
    for (int mt = 0; mt < 4; mt++) {
#pragma unroll
      for (int r = 0; r < 4; r++) {
        int row = m0 + wm + mt * 16 + quad * 4 + r;
        Cout[(size_t)row * N + col] = acc[mt][nt][r] + bv;
      }
    }
  }
}

// ---------------- fused flash attention: static-max, register-P, MFMA row-sums ----
// l computed by an extra ones-B MFMA per kc (Ol accumulates row-sums in row-layout
// C registers): removes all psum VALU adds + every epilogue shuffle. K/V LDS reads
// conflict-free via R9 staging swizzle.
// R4: s_setprio(1) around MFMA clusters (T5) — verified 45.5 -> 43.5 us.
__global__ __launch_bounds__(512, 4) void k_attn(const __bf16* __restrict__ qkv,
                                                 const __bf16* __restrict__ vt,
                                                 __bf16* __restrict__ aout) {
  __shared__ __align__(16) __bf16 smem[32768];   // 64 KB: K dbuf 2x16K, V dbuf 2x16K
  const int t = threadIdx.x;           // 0..511
  const int lane = t & 63, wv = t >> 6;
  const int ln = lane & 15, quad = lane >> 4;
  const int sw8 = (quad ^ ((ln >> 1) & 3)) * 8;

  int gid = blockIdx.x;
  int slot = gid & 7, j = gid >> 3;
  int bh = slot * 4 + (j >> 4);     // 4 (b,h) pairs per XCD slot -> K/V pinned in XCD L2
  int qt0 = j & 15;
  const int b = bh >> 4, h = bh & 15;
  const int q0 = qt0 * 128;

  const __bf16* qbase = qkv + (size_t)b * SEQ * NQKV + h * 192;
  const __bf16* kbase = qbase + 64;
  const __bf16* vbase = vt + (size_t)bh * 64 * SEQ;

  // prologue: stage K(0), V(0) into parity-0 buffers (source-chunk swizzled)
#pragma unroll
  for (int i = 0; i < 2; i++) {
    int tt = i * 512 + t;
    int hh = tt >> 9, row = (tt >> 2) & 127, ch = tt & 3;
    int chs = ch ^ ((row >> 1) & 3);
    async16(kbase + (size_t)row * NQKV + hh * 32 + chs * 8, smem + tt * 8);
  }
#pragma unroll
  for (int i = 0; i < 2; i++) {
    int tt = i * 512 + t;
    int c = tt >> 8, d = (tt >> 2) & 63, w = tt & 3;
    int ws = w ^ ((d >> 1) & 3);
    async16(vbase + (size_t)d * SEQ + c * 32 + ws * 8, smem + 16384 + tt * 8);
  }

  // Q fragments (pre-scaled by CE): wave's 16 q rows, B-operand layout
  bf16x8 qf[2];
#pragma unroll
  for (int dc = 0; dc < 2; dc++)
    qf[dc] = *(const bf16x8*)(qbase + (size_t)(q0 + wv * 16 + ln) * NQKV + dc * 32 + quad * 8);

  union { unsigned u[4]; bf16x8 v; } ones;
  ones.u[0] = ones.u[1] = ones.u[2] = ones.u[3] = 0x3F803F80u;   // bf16 1.0 x8

  const f32x4 zero4 = {0.f, 0.f, 0.f, 0.f};
  f32x4 O[4];
  f32x4 Ol = zero4;                 // row-sums (l) via ones-MFMA, row-layout
#pragma unroll
  for (int dt = 0; dt < 4; dt++) O[dt] = zero4;

  for (int it = 0; it < SEQ / 128; it++) {
    __syncthreads();   // K(it)/V(it) landed; (it-1)'s buffers fully consumed
    const __bf16* Ks = smem + (it & 1) * 8192;
    const __bf16* Vs = smem + 16384 + (it & 1) * 8192;
    if (it + 1 < SEQ / 128) {   // prefetch next tile; flies over this tile's compute
      __bf16* Kd = smem + ((it + 1) & 1) * 8192;
      __bf16* Vd = smem + 16384 + ((it + 1) & 1) * 8192;
      const __bf16* kn = kbase + (size_t)(it + 1) * 128 * NQKV;
      const __bf16* vn = vbase + (it + 1) * 128;
#pragma unroll
      for (int i = 0; i < 2; i++) {
        int tt = i * 512 + t;
        int hh = tt >> 9, row = (tt >> 2) & 127, ch = tt & 3;
        int chs = ch ^ ((row >> 1) & 3);
        async16(kn + (size_t)row * NQKV + hh * 32 + chs * 8, Kd + tt * 8);
      }
#pragma unroll
      for (int i = 0; i < 2; i++) {
        int tt = i * 512 + t;
        int c = tt >> 8, d = (tt >> 2) & 63, w = tt & 3;
        int ws = w ^ ((d >> 1) & 3);
        async16(vn + (size_t)d * SEQ + c * 32 + ws * 8, Vd + tt * 8);
      }
    }

    // S^T = K * Q^T per 16-row blk; P = exp2(S^T) packed to bf16 immediately
    unsigned Pp[8][2];
#pragma unroll
    for (int blk = 0; blk < 8; blk++) {
      bf16x8 kf0 = *(const bf16x8*)(Ks +        (blk * 16 + ln) * 32 + sw8);
      bf16x8 kf1 = *(const bf16x8*)(Ks + 4096 + (blk * 16 + ln) * 32 + sw8);
      __builtin_amdgcn_s_setprio(1);
      f32x4 s = __builtin_amdgcn_mfma_f32_16x16x32_bf16(kf0, qf[0], zero4, 0, 0, 0);
      s = __builtin_amdgcn_mfma_f32_16x16x32_bf16(kf1, qf[1], s, 0, 0, 0);
      __builtin_amdgcn_s_setprio(0);
      Pp[blk][0] = pk2(fexp2(s[0]), fexp2(s[1]));
      Pp[blk][1] = pk2(fexp2(s[2]), fexp2(s[3]));
    }
    // O += P*V; Ol += P*1 (row-sums) — all on the MFMA pipe
#pragma unroll
    for (int kc = 0; kc < 4; kc++) {
      union { bf16x8 v; unsigned u[4]; } pf;
      pf.u[0] = Pp[kc][0]; pf.u[1] = Pp[kc][1];
      pf.u[2] = Pp[kc + 4][0]; pf.u[3] = Pp[kc + 4][1];
      __builtin_amdgcn_s_setprio(1);
      Ol = __builtin_amdgcn_mfma_f32_16x16x32_bf16(pf.v, ones.v, Ol, 0, 0, 0);
#pragma unroll
      for (int dt = 0; dt < 4; dt++) {
        bf16x8 vf = *(const bf16x8*)(Vs + kc * 2048 + (dt * 16 + ln) * 32 + sw8);
        O[dt] = __builtin_amdgcn_mfma_f32_16x16x32_bf16(pf.v, vf, O[dt], 0, 0, 0);
      }
      __builtin_amdgcn_s_setprio(0);
    }
  }

  // epilogue: Ol[r] = l for q-row quad*4+r (same row-layout as O) -> no shuffles.
  __bf16* stage = smem + wv * 1024;   // wave-private 16x64
#pragma unroll
  for (int r = 0; r < 4; r++) {
    float ir = 1.0f / Ol[r];
#pragma unroll
    for (int dt = 0; dt < 4; dt++)
      stage[(quad * 4 + r) * 64 + dt * 16 + ln] = f2bf(O[dt][r] * ir);
  }
  __bf16* obase = aout + (size_t)(b * SEQ + q0 + wv * 16) * HIDDEN + h * 64;
#pragma unroll
  for (int i = 0; i < 2; i++) {
    int tt = i * 64 + lane; int row = tt >> 3, ch = tt & 7;
    *(bf16x8*)(obase + (size_t)row * HIDDEN + ch * 8) = *(const bf16x8*)(stage + row * 64 + ch * 8);
  }
}

extern "C" void kernel_launch(void* const* d_in, const int* in_sizes, int n_in,
                              void* d_out, int out_size, void* d_ws, size_t ws_size,
                              hipStream_t stream) {
  const float* x     = (const float*)d_in[0];
  const float* qkv_w = (const float*)d_in[1];
  const float* qkv_b = (const float*)d_in[2];
  const float* out_w = (const float*)d_in[3];
  const float* out_b = (const float*)d_in[4];

  char* ws = (char*)d_ws;
  __bf16* xb   = (__bf16*)(ws);                       // 4096*1024*2   =  8,388,608
  __bf16* wqkT = (__bf16*)(ws + 8388608);             // 3072*1024*2   =  6,291,456
  __bf16* woT  = (__bf16*)(ws + 14680064);            // 1024*1024*2   =  2,097,152
  __bf16* qkv  = (__bf16*)(ws + 16777216);            // 4096*3072*2   = 25,165,824 (V cols unused)
  __bf16* vt   = (__bf16*)(ws + 41943040);            // 32*64*2048*2  =  8,388,608
  __bf16* aout = (__bf16*)(ws + 50331648);            // 4096*1024*2   =  8,388,608

  k_prep<<<5120, 256, 0, stream>>>(x, xb, qkv_w, wqkT, out_w, woT);
  k_qkv<<<192, 512, 0, stream>>>(xb, wqkT, qkv_b, qkv, vt);
  k_attn<<<512, 512, 0, stream>>>(qkv, vt, aout);
  k_gemm_out<<<512, 256, 0, stream>>>(aout, woT, out_b, (float*)d_out, MTOT, HIDDEN, HIDDEN);
}

// Round 7
// 178.763 us; speedup vs baseline: 1.0523x; 1.0523x over previous
//
#include <hip/hip_runtime.h>
#include <hip/hip_bf16.h>
#include <cstdint>
#include <cstddef>

typedef float  f32x4  __attribute__((ext_vector_type(4)));
typedef __bf16 bf16x8 __attribute__((ext_vector_type(8)));
typedef __bf16 bf16x4 __attribute__((ext_vector_type(4)));

#define HIDDEN 1024
#define SEQ    2048
#define BATCH  2
#define NQKV   3072
#define MTOT   4096

__device__ __forceinline__ __bf16 f2bf(float f) {
  unsigned u = __builtin_bit_cast(unsigned, f);
  u += 0x7FFFu + ((u >> 16) & 1u);          // round-to-nearest-even
  unsigned short s = (unsigned short)(u >> 16);
  return __builtin_bit_cast(__bf16, s);
}

// pack two f32 -> bf16x2 (round-half-up) in 3 VALU: 2 adds + 1 v_perm_b32
__device__ __forceinline__ unsigned pk2(float a, float b) {
  unsigned ua = __builtin_bit_cast(unsigned, a) + 0x8000u;
  unsigned ub = __builtin_bit_cast(unsigned, b) + 0x8000u;
  return __builtin_amdgcn_perm(ub, ua, 0x07060302u);  // {hi16(ub), hi16(ua)}
}

__device__ __forceinline__ float fexp2(float x) {
#if __has_builtin(__builtin_amdgcn_exp2f)
  return __builtin_amdgcn_exp2f(x);   // bare v_exp_f32
#else
  return exp2f(x);
#endif
}

__device__ __forceinline__ void async16(const void* g, void* l) {
  __builtin_amdgcn_global_load_lds((__attribute__((address_space(1))) void*)(g),
                                   (__attribute__((address_space(3))) void*)(l),
                                   16, 0, 0);
}

#define MFMA16(a, b, c) __builtin_amdgcn_mfma_f32_16x16x32_bf16((a), (b), (c), 0, 0, 0)

// ---------------- prep: x->bf16 convert + both weight transposes (one launch) ----
__global__ __launch_bounds__(256) void k_prep(const float* __restrict__ x,
                                              __bf16* __restrict__ xb,
                                              const float* __restrict__ qkv_w,
                                              __bf16* __restrict__ wqkT,
                                              const float* __restrict__ out_w,
                                              __bf16* __restrict__ woT) {
  __shared__ float tile[64][65];
  const int bid = blockIdx.x, t = threadIdx.x;
  if (bid < 4096) {
    int i = bid * 256 + t;
    float4 v = ((const float4*)x)[i];
    bf16x4 o;
    o[0] = f2bf(v.x); o[1] = f2bf(v.y); o[2] = f2bf(v.z); o[3] = f2bf(v.w);
    ((bf16x4*)xb)[i] = o;
    return;
  }
  const float* W; __bf16* WT; int N, bx, by;
  if (bid < 4864) { int g = bid - 4096; W = qkv_w; WT = wqkT; N = NQKV;  bx = g % 48; by = g / 48; }
  else            { int g = bid - 4864; W = out_w; WT = woT;  N = HIDDEN; bx = g % 16; by = g / 16; }
  const int K = HIDDEN;
  int tx = t & 63, ty = t >> 6;
  int n0 = bx * 64, k0 = by * 64;
#pragma unroll
  for (int r = 0; r < 16; r++) {
    int row = r * 4 + ty;
    tile[row][tx] = W[(size_t)(k0 + row) * N + n0 + tx];
  }
  __syncthreads();
#pragma unroll
  for (int i2 = 0; i2 < 2; i2++) {
    int cc = i2 * 256 + t;
    int n = cc >> 3, ch = cc & 7;
    bf16x8 o;
#pragma unroll
    for (int j = 0; j < 8; j++) o[j] = f2bf(tile[ch * 8 + j][n]);
    *(bf16x8*)(WT + (size_t)(n0 + n) * K + k0 + ch * 8) = o;
  }
}

// ---------------- QKV GEMM: 256x256, BK=64, true 8-phase (m201-class) ----------
// R7 = R6 resubmit (container failed twice; schedule re-audited, no hazard
// found -> infra suspect). Hardening vs R6: builtin s_barrier for mid/closing
// barriers (convergent-modeled), no unroll pragma on kt loop.
//   - 8 waves (2M x 4N), per-wave 128x64 out, acc[8][4].
//   - K-tile = 64; 4 phases/K-tile = gray-coded C-quadrants
//     P0:(m0,n0) P1:(m0,n1) P2:(m1,n1) P3:(m1,n0); A frags read once per
//     M-half (P0/P2, 8x ds_read_b128), B frags once per N-pair (P0/P1, 4x).
//   - A/B LDS halves are bit6-STRIPED: half h = rows{bit6==h} so EVERY wave
//     reads A-h0 only at P0, A-h1 only at P2; B slot dead after P1. Staging:
//       P0 stages A(kt+1,h1)  [slot dead since P2 of kt-1]
//       P1 stages A(kt+2,h0)  [dead after P0 of kt: all waves' lgkmcnt(0)
//                              precede P0's closing barrier]
//       P2 stages B(kt+2,h0)  [dead after P1, same argument]
//       P3 stages B(kt+2,h1)  [dead after P1]
//   - counted s_waitcnt vmcnt(6) (3 half-tiles x 2 loads/thread in flight)
//     once per K-tile; never 0 mid-loop; prologue 7 half-tiles; vmcnt(0) only
//     at kt=15. Ledger: top-of-kt = 6 outstanding + 8 issued during kt-1;
//     vmcnt(6) retires the 8 oldest = exactly all of tile kt.
//   - phase body: {ds_reads | stage -> s_barrier -> lgkmcnt(0)+sched_barrier(0)
//     -> setprio(1) 16 MFMA setprio(0) -> s_barrier}.
//   - chunk-XOR swizzle c^(row&7) on stage-source AND read (involution, linear
//     LDS dest; row&7 == ln&7 for all fragment reads).
// LDS 128 KB -> 1 block/CU (by design, as m201). Grid 192, XCD-bijective
// 3bx x 8by rectangles. VFUSE epilogue unchanged.
__global__ __launch_bounds__(512, 2) void k_qkv(const __bf16* __restrict__ A,
                                                const __bf16* __restrict__ BT,
                                                const float* __restrict__ bias,
                                                __bf16* __restrict__ Cout,
                                                __bf16* __restrict__ vt) {
  const int K = HIDDEN;
  __shared__ __align__(16) __bf16 As[2][2][8192];   // [parity][half][128 striped rows x 64 k]
  __shared__ __align__(16) __bf16 Bs[2][2][8192];
  const int t = threadIdx.x;
  const int lane = t & 63, wv = t >> 6;
  const int ln = lane & 15, quad = lane >> 4;
  const int wm = (wv >> 2) * 128, wn = (wv & 3) * 64;

  const int lin = blockIdx.x;
  const int xcd = lin & 7, wi = lin >> 3;          // wi in [0,24)
  const int bxi = (xcd & 3) * 3 + wi % 3;          // [0,12)
  const int byi = (xcd >> 2) * 8 + wi / 3;         // [0,16)
  const int m0 = byi * 256, n0 = bxi * 256;

  // stage one striped half-tile (128 rows x 64 k), 2 loads/thread
  auto stA = [&](int kt, int h) {
    __bf16* dst = &As[kt & 1][h][0];
    const __bf16* src = A + (size_t)m0 * K + kt * 64;
#pragma unroll
    for (int i = 0; i < 2; i++) {
      int tt = i * 512 + t;
      int sr = tt >> 3, ch = tt & 7;
      int gr = (sr & 63) + ((sr >> 6) << 7) + h * 64;   // striped row
      async16(src + (size_t)gr * K + ((ch ^ (sr & 7)) * 8), dst + tt * 8);
    }
  };
  auto stB = [&](int kt, int h) {
    __bf16* dst = &Bs[kt & 1][h][0];
    const __bf16* src = BT + (size_t)n0 * K + kt * 64;
#pragma unroll
    for (int i = 0; i < 2; i++) {
      int tt = i * 512 + t;
      int sr = tt >> 3, ch = tt & 7;
      int gr = (sr & 63) + ((sr >> 6) << 7) + h * 64;
      async16(src + (size_t)gr * K + ((ch ^ (sr & 7)) * 8), dst + tt * 8);
    }
  };

  const f32x4 zero4 = {0.f, 0.f, 0.f, 0.f};
  f32x4 acc[8][4];
#pragma unroll
  for (int i = 0; i < 8; i++)
#pragma unroll
    for (int j = 0; j < 4; j++) acc[i][j] = zero4;

  // prologue: kt0 complete + kt1 {A-h0, B-h0, B-h1}  (7 half-tiles, 14 loads)
  stA(0, 0); stA(0, 1); stB(0, 0); stB(0, 1);
  stA(1, 0); stB(1, 0); stB(1, 1);

  bf16x8 af[4][2], bf[4][2];
  const int sra = ln + ((wv >> 2) << 6);        // + m*16 : in-half A row
  const int scb = ln + (((wv & 3) >> 1) << 6);  // + n*16 : in-half B row
  const int swz = ln & 7;

  const int NT = K / 64;   // 16
  for (int kt = 0; kt < NT; kt++) {
    const int p = kt & 1;
    if (kt < NT - 1) asm volatile("s_waitcnt vmcnt(6)" ::: "memory");
    else             asm volatile("s_waitcnt vmcnt(0)" ::: "memory");
    __builtin_amdgcn_s_barrier();
    const __bf16* Bh = &Bs[p][wv & 1][0];
    // ---------------- P0: quadrant (m0, n0); reads A-h0(8) + B lo(4)
    {
      const __bf16* Ah = &As[p][0][0];
#pragma unroll
      for (int m = 0; m < 4; m++)
#pragma unroll
        for (int kk = 0; kk < 2; kk++)
          af[m][kk] = *(const bf16x8*)(Ah + (sra + m * 16) * 64 + (((kk * 4 + quad) ^ swz) * 8));
#pragma unroll
      for (int n = 0; n < 2; n++)
#pragma unroll
        for (int kk = 0; kk < 2; kk++)
          bf[n][kk] = *(const bf16x8*)(Bh + (scb + n * 16) * 64 + (((kk * 4 + quad) ^ swz) * 8));
      if (kt + 1 < NT) stA(kt + 1, 1);
      __builtin_amdgcn_s_barrier();
      asm volatile("s_waitcnt lgkmcnt(0)" ::: "memory");
      __builtin_amdgcn_sched_barrier(0);
      __builtin_amdgcn_s_setprio(1);
#pragma unroll
      for (int m = 0; m < 4; m++)
#pragma unroll
        for (int n = 0; n < 2; n++) {
          acc[m][n] = MFMA16(af[m][0], bf[n][0], acc[m][n]);
          acc[m][n] = MFMA16(af[m][1], bf[n][1], acc[m][n]);
        }
      __builtin_amdgcn_s_setprio(0);
      __builtin_amdgcn_s_barrier();
    }
    // ---------------- P1: quadrant (m0, n1); reads B hi(4)
    {
#pragma unroll
      for (int n = 2; n < 4; n++)
#pragma unroll
        for (int kk = 0; kk < 2; kk++)
          bf[n][kk] = *(const bf16x8*)(Bh + (scb + n * 16) * 64 + (((kk * 4 + quad) ^ swz) * 8));
      if (kt + 2 < NT) stA(kt + 2, 0);
      __builtin_amdgcn_s_barrier();
      asm volatile("s_waitcnt lgkmcnt(0)" ::: "memory");
      __builtin_amdgcn_sched_barrier(0);
      __builtin_amdgcn_s_setprio(1);
#pragma unroll
      for (int m = 0; m < 4; m++)
#pragma unroll
        for (int n = 2; n < 4; n++) {
          acc[m][n] = MFMA16(af[m][0], bf[n][0], acc[m][n]);
          acc[m][n] = MFMA16(af[m][1], bf[n][1], acc[m][n]);
        }
      __builtin_amdgcn_s_setprio(0);
      __builtin_amdgcn_s_barrier();
    }
    // ---------------- P2: quadrant (m1, n1); reads A-h1(8)
    {
      const __bf16* Ah = &As[p][1][0];
#pragma unroll
      for (int m = 0; m < 4; m++)
#pragma unroll
        for (int kk = 0; kk < 2; kk++)
          af[m][kk] = *(const bf16x8*)(Ah + (sra + m * 16) * 64 + (((kk * 4 + quad) ^ swz) * 8));
      if (kt + 2 < NT) stB(kt + 2, 0);
      __builtin_amdgcn_s_barrier();
      asm volatile("s_waitcnt lgkmcnt(0)" ::: "memory");
      __builtin_amdgcn_sched_barrier(0);
      __builtin_amdgcn_s_setprio(1);
#pragma unroll
      for (int m = 0; m < 4; m++)
#pragma unroll
        for (int n = 2; n < 4; n++) {
          acc[4 + m][n] = MFMA16(af[m][0], bf[n][0], acc[4 + m][n]);
          acc[4 + m][n] = MFMA16(af[m][1], bf[n][1], acc[4 + m][n]);
        }
      __builtin_amdgcn_s_setprio(0);
      __builtin_amdgcn_s_barrier();
    }
    // ---------------- P3: quadrant (m1, n0); no new reads (regs from P2/P0)
    {
      if (kt + 2 < NT) stB(kt + 2, 1);
      __builtin_amdgcn_s_setprio(1);
#pragma unroll
      for (int m = 0; m < 4; m++)
#pragma unroll
        for (int n = 0; n < 2; n++) {
          acc[4 + m][n] = MFMA16(af[m][0], bf[n][0], acc[4 + m][n]);
          acc[4 + m][n] = MFMA16(af[m][1], bf[n][1], acc[4 + m][n]);
        }
      __builtin_amdgcn_s_setprio(0);
      // closing barrier is the next kt's top {vmcnt; s_barrier}
    }
  }

  const float CE = 0.125f * 1.44269504089f;
#pragma unroll
  for (int nt = 0; nt < 4; nt++) {
    int g = n0 + wn + nt * 16;      // lane-uniform 16-col group base
    int col = g + ln;
    float bv = bias[col];
    int off = g % 192;
    if (off < 128) {
      float scl = (off < 64) ? CE : 1.0f;    // pre-scale Q by CE
#pragma unroll
      for (int mt = 0; mt < 8; mt++) {
#pragma unroll
        for (int r = 0; r < 4; r++) {
          int row = m0 + wm + mt * 16 + quad * 4 + r;
          Cout[(size_t)row * NQKV + col] = f2bf((acc[mt][nt][r] + bv) * scl);
        }
      }
    } else {
      // V path: vt[bh][d][sblk*128 + p], p = permuted in-block position
      int hg = g / 192;
      int d  = off - 128 + ln;
#pragma unroll
      for (int mt = 0; mt < 8; mt++) {
        int rowb = m0 + wm + mt * 16;        // + quad*4 + r
        int bb = rowb >> 11;
        int s  = rowb & 2047;
        int sblk = s >> 7;
        int blk  = (s >> 4) & 7;             // (s%128)/16
        int pp = (blk & 3) * 32 + quad * 8 + ((blk >> 2) << 2);
        uint2 o;
        o.x = pk2(acc[mt][nt][0] + bv, acc[mt][nt][1] + bv);
        o.y = pk2(acc[mt][nt][2] + bv, acc[mt][nt][3] + bv);
        *(uint2*)(vt + ((size_t)((bb * 16 + hg) * 64 + d)) * SEQ + sblk * 128 + pp) = o;
      }
    }
  }
}

// ---------------- out GEMM: C[M][N] = A[M][K] * BT[N][K]^T + bias (f32 out) ----
// R3 form (2-buffer dbuf prefetch, drain-0): kept for N=1024 where 128x64 tiles
// give 512 blocks = 2/CU.
__global__ __launch_bounds__(256, 4) void k_gemm_out(const __bf16* __restrict__ A,
                                                     const __bf16* __restrict__ BT,
                                                     const float* __restrict__ bias,
                                                     float* __restrict__ Cout,
                                                     int M, int N, int K) {
  constexpr int TN = 64;
  __shared__ __align__(16) __bf16 As[2 * 128 * 32];
  __shared__ __align__(16) __bf16 Bs[2 * TN * 32];
  const int t = threadIdx.x;
  const int lane = t & 63, wv = t >> 6;
  const int ln = lane & 15, quad = lane >> 4;
  const int sw8 = (quad ^ ((ln >> 1) & 3)) * 8;
  const int wm = (wv & 1) * 64, wn = (wv >> 1) * (TN / 2);

  const int nbx = N / TN;                 // 16
  const int cx = nbx >> 1;                // 8
  const int lin = blockIdx.x;
  const int xcd = lin & 7, wi = lin >> 3;
  const int bxi = (xcd & 1) * cx + wi % cx;
  const int byi = (xcd >> 1) * 8 + wi / cx;
  const int m0 = byi * 128, n0 = bxi * TN;

  auto stage = [&](int k0, int p) {
    __bf16* Ad = As + p * (128 * 32);
    __bf16* Bd = Bs + p * (TN * 32);
#pragma unroll
    for (int i = 0; i < 2; i++) {
      int tt = i * 256 + t;
      int row = tt >> 2, ch = tt & 3;
      int chs = ch ^ ((row >> 1) & 3);
      async16(A + (size_t)(m0 + row) * K + k0 + chs * 8, Ad + tt * 8);
    }
    {
      int tt = t;
      int row = tt >> 2, ch = tt & 3;
      int chs = ch ^ ((row >> 1) & 3);
      async16(BT + (size_t)(n0 + row) * K + k0 + chs * 8, Bd + tt * 8);
    }
  };

  const f32x4 zero4 = {0.f, 0.f, 0.f, 0.f};
  f32x4 acc[4][2];
#pragma unroll
  for (int i = 0; i < 4; i++)
#pragma unroll
    for (int j = 0; j < 2; j++) acc[i][j] = zero4;

  stage(0, 0);
  const int NIT = K / 32;
  for (int it = 0; it < NIT; it++) {
    __syncthreads();
    if (it + 1 < NIT) stage((it + 1) * 32, (it + 1) & 1);
    const __bf16* Asb = As + (it & 1) * (128 * 32);
    const __bf16* Bsb = Bs + (it & 1) * (TN * 32);
    bf16x8 af[4], bfr[2];
#pragma unroll
    for (int x = 0; x < 4; x++)
      af[x] = *(const bf16x8*)(Asb + (wm + x * 16 + ln) * 32 + sw8);
#pragma unroll
    for (int x = 0; x < 2; x++)
      bfr[x] = *(const bf16x8*)(Bsb + (wn + x * 16 + ln) * 32 + sw8);
#pragma unroll
    for (int mt = 0; mt < 4; mt++)
#pragma unroll
      for (int nt = 0; nt < 2; nt++)
        acc[mt][nt] = MFMA16(af[mt], bfr[nt], acc[mt][nt]);
  }
#pragma unroll
  for (int nt = 0; nt < 2; nt++) {
    int col = n0 + wn + nt * 16 + ln;
    float bv = bias[col];
#pragma unroll
    for (int mt = 0; mt < 4; mt++) {
#pragma unroll
      for (int r = 0; r < 4; r++) {
        int row = m0 + wm + mt * 16 + quad * 4 + r;
        Cout[(size_t)row * N + col] = acc[mt][nt][r] + bv;
      }
    }
  }
}

// ---------------- fused flash attention: static-max, register-P, MFMA row-sums ----
// R4: s_setprio(1) around MFMA clusters (T5) — verified 45.5 -> 43.5 us.
__global__ __launch_bounds__(512, 4) void k_attn(const __bf16* __restrict__ qkv,
                                                 const __bf16* __restrict__ vt,
                                                 __bf16* __restrict__ aout) {
  __shared__ __align__(16) __bf16 smem[32768];   // 64 KB: K dbuf 2x16K, V dbuf 2x16K
  const int t = threadIdx.x;           // 0..511
  const int lane = t & 63, wv = t >> 6;
  const int ln = lane & 15, quad = lane >> 4;
  const int sw8 = (quad ^ ((ln >> 1) & 3)) * 8;

  int gid = blockIdx.x;
  int slot = gid & 7, j = gid >> 3;
  int bh = slot * 4 + (j >> 4);     // 4 (b,h) pairs per XCD slot -> K/V pinned in XCD L2
  int qt0 = j & 15;
  const int b = bh >> 4, h = bh & 15;
  const int q0 = qt0 * 128;

  const __bf16* qbase = qkv + (size_t)b * SEQ * NQKV + h * 192;
  const __bf16* kbase = qbase + 64;
  const __bf16* vbase = vt + (size_t)bh * 64 * SEQ;

  // prologue: stage K(0), V(0) into parity-0 buffers (source-chunk swizzled)
#pragma unroll
  for (int i = 0; i < 2; i++) {
    int tt = i * 512 + t;
    int hh = tt >> 9, row = (tt >> 2) & 127, ch = tt & 3;
    int chs = ch ^ ((row >> 1) & 3);
    async16(kbase + (size_t)row * NQKV + hh * 32 + chs * 8, smem + tt * 8);
  }
#pragma unroll
  for (int i = 0; i < 2; i++) {
    int tt = i * 512 + t;
    int c = tt >> 8, d = (tt >> 2) & 63, w = tt & 3;
    int ws = w ^ ((d >> 1) & 3);
    async16(vbase + (size_t)d * SEQ + c * 32 + ws * 8, smem + 16384 + tt * 8);
  }

  // Q fragments (pre-scaled by CE): wave's 16 q rows, B-operand layout
  bf16x8 qf[2];
#pragma unroll
  for (int dc = 0; dc < 2; dc++)
    qf[dc] = *(const bf16x8*)(qbase + (size_t)(q0 + wv * 16 + ln) * NQKV + dc * 32 + quad * 8);

  union { unsigned u[4]; bf16x8 v; } ones;
  ones.u[0] = ones.u[1] = ones.u[2] = ones.u[3] = 0x3F803F80u;   // bf16 1.0 x8

  const f32x4 zero4 = {0.f, 0.f, 0.f, 0.f};
  f32x4 O[4];
  f32x4 Ol = zero4;                 // row-sums (l) via ones-MFMA, row-layout
#pragma unroll
  for (int dt = 0; dt < 4; dt++) O[dt] = zero4;

  for (int it = 0; it < SEQ / 128; it++) {
    __syncthreads();   // K(it)/V(it) landed; (it-1)'s buffers fully consumed
    const __bf16* Ks = smem + (it & 1) * 8192;
    const __bf16* Vs = smem + 16384 + (it & 1) * 8192;
    if (it + 1 < SEQ / 128) {   // prefetch next tile; flies over this tile's compute
      __bf16* Kd = smem + ((it + 1) & 1) * 8192;
      __bf16* Vd = smem + 16384 + ((it + 1) & 1) * 8192;
      const __bf16* kn = kbase + (size_t)(it + 1) * 128 * NQKV;
      const __bf16* vn = vbase + (it + 1) * 128;
#pragma unroll
      for (int i = 0; i < 2; i++) {
        int tt = i * 512 + t;
        int hh = tt >> 9, row = (tt >> 2) & 127, ch = tt & 3;
        int chs = ch ^ ((row >> 1) & 3);
        async16(kn + (size_t)row * NQKV + hh * 32 + chs * 8, Kd + tt * 8);
      }
#pragma unroll
      for (int i = 0; i < 2; i++) {
        int tt = i * 512 + t;
        int c = tt >> 8, d = (tt >> 2) & 63, w = tt & 3;
        int ws = w ^ ((d >> 1) & 3);
        async16(vn + (size_t)d * SEQ + c * 32 + ws * 8, Vd + tt * 8);
      }
    }

    // S^T = K * Q^T per 16-row blk; P = exp2(S^T) packed to bf16 immediately
    unsigned Pp[8][2];
#pragma unroll
    for (int blk = 0; blk < 8; blk++) {
      bf16x8 kf0 = *(const bf16x8*)(Ks +        (blk * 16 + ln) * 32 + sw8);
      bf16x8 kf1 = *(const bf16x8*)(Ks + 4096 + (blk * 16 + ln) * 32 + sw8);
      __builtin_amdgcn_s_setprio(1);
      f32x4 s = MFMA16(kf0, qf[0], zero4);
      s = MFMA16(kf1, qf[1], s);
      __builtin_amdgcn_s_setprio(0);
      Pp[blk][0] = pk2(fexp2(s[0]), fexp2(s[1]));
      Pp[blk][1] = pk2(fexp2(s[2]), fexp2(s[3]));
    }
    // O += P*V; Ol += P*1 (row-sums) — all on the MFMA pipe
#pragma unroll
    for (int kc = 0; kc < 4; kc++) {
      union { bf16x8 v; unsigned u[4]; } pf;
      pf.u[0] = Pp[kc][0]; pf.u[1] = Pp[kc][1];
      pf.u[2] = Pp[kc + 4][0]; pf.u[3] = Pp[kc + 4][1];
      __builtin_amdgcn_s_setprio(1);
      Ol = MFMA16(pf.v, ones.v, Ol);
#pragma unroll
      for (int dt = 0; dt < 4; dt++) {
        bf16x8 vf = *(const bf16x8*)(Vs + kc * 2048 + (dt * 16 + ln) * 32 + sw8);
        O[dt] = MFMA16(pf.v, vf, O[dt]);
      }
      __builtin_amdgcn_s_setprio(0);
    }
  }

  // epilogue: Ol[r] = l for q-row quad*4+r (same row-layout as O) -> no shuffles.
  __bf16* stage = smem + wv * 1024;   // wave-private 16x64
#pragma unroll
  for (int r = 0; r < 4; r++) {
    float ir = 1.0f / Ol[r];
#pragma unroll
    for (int dt = 0; dt < 4; dt++)
      stage[(quad * 4 + r) * 64 + dt * 16 + ln] = f2bf(O[dt][r] * ir);
  }
  __bf16* obase = aout + (size_t)(b * SEQ + q0 + wv * 16) * HIDDEN + h * 64;
#pragma unroll
  for (int i = 0; i < 2; i++) {
    int tt = i * 64 + lane; int row = tt >> 3, ch = tt & 7;
    *(bf16x8*)(obase + (size_t)row * HIDDEN + ch * 8) = *(const bf16x8*)(stage + row * 64 + ch * 8);
  }
}

extern "C" void kernel_launch(void* const* d_in, const int* in_sizes, int n_in,
                              void* d_out, int out_size, void* d_ws, size_t ws_size,
                              hipStream_t stream) {
  const float* x     = (const float*)d_in[0];
  const float* qkv_w = (const float*)d_in[1];
  const float* qkv_b = (const float*)d_in[2];
  const float* out_w = (const float*)d_in[3];
  const float* out_b = (const float*)d_in[4];

  char* ws = (char*)d_ws;
  __bf16* xb   = (__bf16*)(ws);                       // 4096*1024*2   =  8,388,608
  __bf16* wqkT = (__bf16*)(ws + 8388608);             // 3072*1024*2   =  6,291,456
  __bf16* woT  = (__bf16*)(ws + 14680064);            // 1024*1024*2   =  2,097,152
  __bf16* qkv  = (__bf16*)(ws + 16777216);            // 4096*3072*2   = 25,165,824 (V cols unused)
  __bf16* vt   = (__bf16*)(ws + 41943040);            // 32*64*2048*2  =  8,388,608
  __bf16* aout = (__bf16*)(ws + 50331648);            // 4096*1024*2   =  8,388,608

  k_prep<<<5120, 256, 0, stream>>>(x, xb, qkv_w, wqkT, out_w, woT);
  k_qkv<<<192, 512, 0, stream>>>(xb, wqkT, qkv_b, qkv, vt);
  k_attn<<<512, 512, 0, stream>>>(qkv, vt, aout);
  k_gemm_out<<<512, 256, 0, stream>>>(aout, woT, out_b, (float*)d_out, MTOT, HIDDEN, HIDDEN);
}

// Round 8
// 177.430 us; speedup vs baseline: 1.0602x; 1.0075x over previous
//
#include <hip/hip_runtime.h>
#include <hip/hip_bf16.h>
#include <cstdint>
#include <cstddef>

typedef float  f32x4  __attribute__((ext_vector_type(4)));
typedef __bf16 bf16x8 __attribute__((ext_vector_type(8)));
typedef __bf16 bf16x4 __attribute__((ext_vector_type(4)));

#define HIDDEN 1024
#define SEQ    2048
#define BATCH  2
#define NQKV   3072
#define MTOT   4096

__device__ __forceinline__ __bf16 f2bf(float f) {
  unsigned u = __builtin_bit_cast(unsigned, f);
  u += 0x7FFFu + ((u >> 16) & 1u);          // round-to-nearest-even
  unsigned short s = (unsigned short)(u >> 16);
  return __builtin_bit_cast(__bf16, s);
}

// pack two f32 -> bf16x2 (round-half-up) in 3 VALU: 2 adds + 1 v_perm_b32
__device__ __forceinline__ unsigned pk2(float a, float b) {
  unsigned ua = __builtin_bit_cast(unsigned, a) + 0x8000u;
  unsigned ub = __builtin_bit_cast(unsigned, b) + 0x8000u;
  return __builtin_amdgcn_perm(ub, ua, 0x07060302u);  // {hi16(ub), hi16(ua)}
}

__device__ __forceinline__ float fexp2(float x) {
#if __has_builtin(__builtin_amdgcn_exp2f)
  return __builtin_amdgcn_exp2f(x);   // bare v_exp_f32
#else
  return exp2f(x);
#endif
}

__device__ __forceinline__ void async16(const void* g, void* l) {
  __builtin_amdgcn_global_load_lds((__attribute__((address_space(1))) void*)(g),
                                   (__attribute__((address_space(3))) void*)(l),
                                   16, 0, 0);
}

#define MFMA16(a, b, c) __builtin_amdgcn_mfma_f32_16x16x32_bf16((a), (b), (c), 0, 0, 0)

// ---------------- prep: x->bf16 convert + both weight transposes (one launch) ----
__global__ __launch_bounds__(256) void k_prep(const float* __restrict__ x,
                                              __bf16* __restrict__ xb,
                                              const float* __restrict__ qkv_w,
                                              __bf16* __restrict__ wqkT,
                                              const float* __restrict__ out_w,
                                              __bf16* __restrict__ woT) {
  __shared__ float tile[64][65];
  const int bid = blockIdx.x, t = threadIdx.x;
  if (bid < 4096) {
    int i = bid * 256 + t;
    float4 v = ((const float4*)x)[i];
    bf16x4 o;
    o[0] = f2bf(v.x); o[1] = f2bf(v.y); o[2] = f2bf(v.z); o[3] = f2bf(v.w);
    ((bf16x4*)xb)[i] = o;
    return;
  }
  const float* W; __bf16* WT; int N, bx, by;
  if (bid < 4864) { int g = bid - 4096; W = qkv_w; WT = wqkT; N = NQKV;  bx = g % 48; by = g / 48; }
  else            { int g = bid - 4864; W = out_w; WT = woT;  N = HIDDEN; bx = g % 16; by = g / 16; }
  const int K = HIDDEN;
  int tx = t & 63, ty = t >> 6;
  int n0 = bx * 64, k0 = by * 64;
#pragma unroll
  for (int r = 0; r < 16; r++) {
    int row = r * 4 + ty;
    tile[row][tx] = W[(size_t)(k0 + row) * N + n0 + tx];
  }
  __syncthreads();
#pragma unroll
  for (int i2 = 0; i2 < 2; i2++) {
    int cc = i2 * 256 + t;
    int n = cc >> 3, ch = cc & 7;
    bf16x8 o;
#pragma unroll
    for (int j = 0; j < 8; j++) o[j] = f2bf(tile[ch * 8 + j][n]);
    *(bf16x8*)(WT + (size_t)(n0 + n) * K + k0 + ch * 8) = o;
  }
}

// ---------------- QKV GEMM: 256x192, BK=64, 4-phase counted schedule ------------
// R8: R7's 256x256 grid was 16x12 = 192 blocks on 256 CUs = 75% CU utilization by
// construction. BN=192 -> grid 16x16 = 256 blocks = exactly 1/CU (100%), keeping
// the R7-verified phase skeleton.
//   - 8 waves (2M x 4N), per-wave 128x48, acc[8][3].
//   - phases = (m-half x k-half), 12 MFMA each:
//     P0: m-lo,k0-31   reads a0[4]+b0[3]; stages A(kt+1,h1)
//     P1: m-lo,k32-63  reads a1[4]+b1[3]; no stage
//     P2: m-hi,k0-31   reads a0[4];       stages A(kt+2,h0)
//     P3: m-hi,k32-63  reads a1[4];       stages B(kt+2)
//     (b0/b1 stay live P0/P1 -> P2/P3; each {reads; stage; barrier; lgkmcnt(0);
//      sched_barrier; setprio(1) MFMA setprio(0); barrier})
//   - A halves bit-striped as in R7 (half h = first/second 64 rows of each wave
//     m-half), so A-h0 is read only at P0/P1, A-h1 only at P2/P3.
//   - B tile unsplit 192x64 (24 KB), staged in one 3-load call at P3.
//   - vmcnt ledger (per-thread: stA=2, stB=3): top-of-kt FIFO =
//     [A(kt,h0)2, B(kt)3, A(kt,h1)2, A(kt+1,h0)2, B(kt+1)3]; vmcnt(5) retires
//     exactly tile kt, keeps tile kt+1's 5. Prologue 12 loads
//     {A0h0,B0,A0h1,A1h0,B1}; vmcnt(0) only at kt=15.
//   - Slot liveness (audited): every staging write lands >=1 barrier after the
//     slot's last completed read (reads complete at that phase's lgkmcnt(0),
//     which precedes the phase's closing barrier; staging is issued after it).
//   - chunk-XOR swizzle ch^(row&7) on stage-source AND read (involution; all
//     fragment rows have row&7 == ln&7 since 48/16/64 are multiples of 8).
// LDS 112 KB -> 1 block/CU. Grid 256 = 8 XCDs x 32, each XCD a 4bx x 8by
// rectangle (bijective). VFUSE epilogue: n0 % 192 == 0 so off = wn+nt*16;
// 16-col groups never straddle Q/K/V.
__global__ __launch_bounds__(512, 2) void k_qkv(const __bf16* __restrict__ A,
                                                const __bf16* __restrict__ BT,
                                                const float* __restrict__ bias,
                                                __bf16* __restrict__ Cout,
                                                __bf16* __restrict__ vt) {
  const int K = HIDDEN;
  __shared__ __align__(16) __bf16 As[2][2][8192];   // [parity][half][128 striped rows x 64 k]
  __shared__ __align__(16) __bf16 Bs[2][12288];     // [parity][192 rows x 64 k]
  const int t = threadIdx.x;
  const int lane = t & 63, wv = t >> 6;
  const int ln = lane & 15, quad = lane >> 4;
  const int wm = (wv >> 2) * 128, wn = (wv & 3) * 48;

  const int lin = blockIdx.x;
  const int xcd = lin & 7, wi = lin >> 3;          // wi in [0,32)
  const int bxi = (xcd & 3) * 4 + (wi & 3);        // [0,16)
  const int byi = (xcd >> 2) * 8 + (wi >> 2);      // [0,16)
  const int m0 = byi * 256, n0 = bxi * 192;

  // stage one striped A half-tile (128 rows x 64 k), 2 loads/thread
  auto stA = [&](int kt, int h) {
    __bf16* dst = &As[kt & 1][h][0];
    const __bf16* src = A + (size_t)m0 * K + kt * 64;
#pragma unroll
    for (int i = 0; i < 2; i++) {
      int tt = i * 512 + t;
      int sr = tt >> 3, ch = tt & 7;
      int gr = (sr & 63) + ((sr >> 6) << 7) + h * 64;   // striped row
      async16(src + (size_t)gr * K + ((ch ^ (sr & 7)) * 8), dst + tt * 8);
    }
  };
  // stage full B tile (192 rows x 64 k), 3 loads/thread
  auto stB = [&](int kt) {
    __bf16* dst = &Bs[kt & 1][0];
    const __bf16* src = BT + (size_t)n0 * K + kt * 64;
#pragma unroll
    for (int i = 0; i < 3; i++) {
      int tt = i * 512 + t;
      int row = tt >> 3, ch = tt & 7;
      async16(src + (size_t)row * K + ((ch ^ (row & 7)) * 8), dst + tt * 8);
    }
  };

  const f32x4 zero4 = {0.f, 0.f, 0.f, 0.f};
  f32x4 acc[8][3];
#pragma unroll
  for (int i = 0; i < 8; i++)
#pragma unroll
    for (int j = 0; j < 3; j++) acc[i][j] = zero4;

  // prologue (FIFO must be A(0,h0), B(0), A(0,h1), A(1,h0), B(1) = 12 loads)
  stA(0, 0); stB(0); stA(0, 1); stA(1, 0); stB(1);

  bf16x8 a0[4], a1[4], b0[3], b1[3];
  const int sra = ln + ((wv >> 2) << 6);        // in-half A row base (+ m*16)
  const int srb = (wv & 3) * 48 + ln;           // B row base (+ nt*16)
  const int swz = ln & 7;

  const int NT = K / 64;   // 16
  for (int kt = 0; kt < NT; kt++) {
    const int p = kt & 1;
    if (kt < NT - 1) asm volatile("s_waitcnt vmcnt(5)" ::: "memory");
    else             asm volatile("s_waitcnt vmcnt(0)" ::: "memory");
    __builtin_amdgcn_s_barrier();
    const __bf16* A0 = &As[p][0][0];
    const __bf16* A1 = &As[p][1][0];
    const __bf16* Bb = &Bs[p][0];
    // ---------------- P0: m-lo x k0-31
    {
#pragma unroll
      for (int m = 0; m < 4; m++)
        a0[m] = *(const bf16x8*)(A0 + (sra + m * 16) * 64 + ((quad ^ swz) * 8));
#pragma unroll
      for (int n = 0; n < 3; n++)
        b0[n] = *(const bf16x8*)(Bb + (srb + n * 16) * 64 + ((quad ^ swz) * 8));
      if (kt + 1 < NT) stA(kt + 1, 1);
      __builtin_amdgcn_s_barrier();
      asm volatile("s_waitcnt lgkmcnt(0)" ::: "memory");
      __builtin_amdgcn_sched_barrier(0);
      __builtin_amdgcn_s_setprio(1);
#pragma unroll
      for (int m = 0; m < 4; m++)
#pragma unroll
        for (int n = 0; n < 3; n++)
          acc[m][n] = MFMA16(a0[m], b0[n], acc[m][n]);
      __builtin_amdgcn_s_setprio(0);
      __builtin_amdgcn_s_barrier();
    }
    // ---------------- P1: m-lo x k32-63
    {
#pragma unroll
      for (int m = 0; m < 4; m++)
        a1[m] = *(const bf16x8*)(A0 + (sra + m * 16) * 64 + (((4 + quad) ^ swz) * 8));
#pragma unroll
      for (int n = 0; n < 3; n++)
        b1[n] = *(const bf16x8*)(Bb + (srb + n * 16) * 64 + (((4 + quad) ^ swz) * 8));
      __builtin_amdgcn_s_barrier();
      asm volatile("s_waitcnt lgkmcnt(0)" ::: "memory");
      __builtin_amdgcn_sched_barrier(0);
      __builtin_amdgcn_s_setprio(1);
#pragma unroll
      for (int m = 0; m < 4; m++)
#pragma unroll
        for (int n = 0; n < 3; n++)
          acc[m][n] = MFMA16(a1[m], b1[n], acc[m][n]);
      __builtin_amdgcn_s_setprio(0);
      __builtin_amdgcn_s_barrier();
    }
    // ---------------- P2: m-hi x k0-31 (b0 still live)
    {
#pragma unroll
      for (int m = 0; m < 4; m++)
        a0[m] = *(const bf16x8*)(A1 + (sra + m * 16) * 64 + ((quad ^ swz) * 8));
      if (kt + 2 < NT) stA(kt + 2, 0);
      __builtin_amdgcn_s_barrier();
      asm volatile("s_waitcnt lgkmcnt(0)" ::: "memory");
      __builtin_amdgcn_sched_barrier(0);
      __builtin_amdgcn_s_setprio(1);
#pragma unroll
      for (int m = 0; m < 4; m++)
#pragma unroll
        for (int n = 0; n < 3; n++)
          acc[4 + m][n] = MFMA16(a0[m], b0[n], acc[4 + m][n]);
      __builtin_amdgcn_s_setprio(0);
      __builtin_amdgcn_s_barrier();
    }
    // ---------------- P3: m-hi x k32-63 (b1 still live)
    {
#pragma unroll
      for (int m = 0; m < 4; m++)
        a1[m] = *(const bf16x8*)(A1 + (sra + m * 16) * 64 + (((4 + quad) ^ swz) * 8));
      if (kt + 2 < NT) stB(kt + 2);
      __builtin_amdgcn_s_barrier();
      asm volatile("s_waitcnt lgkmcnt(0)" ::: "memory");
      __builtin_amdgcn_sched_barrier(0);
      __builtin_amdgcn_s_setprio(1);
#pragma unroll
      for (int m = 0; m < 4; m++)
#pragma unroll
        for (int n = 0; n < 3; n++)
          acc[4 + m][n] = MFMA16(a1[m], b1[n], acc[4 + m][n]);
      __builtin_amdgcn_s_setprio(0);
      // closing barrier is the next kt's top {vmcnt; s_barrier}
    }
  }

  const float CE = 0.125f * 1.44269504089f;
#pragma unroll
  for (int nt = 0; nt < 3; nt++) {
    int g = n0 + wn + nt * 16;      // lane-uniform 16-col group base
    int col = g + ln;
    float bv = bias[col];
    int off = g % 192;
    if (off < 128) {
      float scl = (off < 64) ? CE : 1.0f;    // pre-scale Q by CE
#pragma unroll
      for (int mt = 0; mt < 8; mt++) {
#pragma unroll
        for (int r = 0; r < 4; r++) {
          int row = m0 + wm + mt * 16 + quad * 4 + r;
          Cout[(size_t)row * NQKV + col] = f2bf((acc[mt][nt][r] + bv) * scl);
        }
      }
    } else {
      // V path: vt[bh][d][sblk*128 + p], p = permuted in-block position
      int hg = g / 192;
      int d  = off - 128 + ln;
#pragma unroll
      for (int mt = 0; mt < 8; mt++) {
        int rowb = m0 + wm + mt * 16;        // + quad*4 + r
        int bb = rowb >> 11;
        int s  = rowb & 2047;
        int sblk = s >> 7;
        int blk  = (s >> 4) & 7;             // (s%128)/16
        int pp = (blk & 3) * 32 + quad * 8 + ((blk >> 2) << 2);
        uint2 o;
        o.x = pk2(acc[mt][nt][0] + bv, acc[mt][nt][1] + bv);
        o.y = pk2(acc[mt][nt][2] + bv, acc[mt][nt][3] + bv);
        *(uint2*)(vt + ((size_t)((bb * 16 + hg) * 64 + d)) * SEQ + sblk * 128 + pp) = o;
      }
    }
  }
}

// ---------------- out GEMM: C[M][N] = A[M][K] * BT[N][K]^T + bias (f32 out) ----
// R3 form (2-buffer dbuf prefetch, drain-0): kept for N=1024 where 128x64 tiles
// give 512 blocks = 2/CU.
__global__ __launch_bounds__(256, 4) void k_gemm_out(const __bf16* __restrict__ A,
                                                     const __bf16* __restrict__ BT,
                                                     const float* __restrict__ bias,
                                                     float* __restrict__ Cout,
                                                     int M, int N, int K) {
  constexpr int TN = 64;
  __shared__ __align__(16) __bf16 As[2 * 128 * 32];
  __shared__ __align__(16) __bf16 Bs[2 * TN * 32];
  const int t = threadIdx.x;
  const int lane = t & 63, wv = t >> 6;
  const int ln = lane & 15, quad = lane >> 4;
  const int sw8 = (quad ^ ((ln >> 1) & 3)) * 8;
  const int wm = (wv & 1) * 64, wn = (wv >> 1) * (TN / 2);

  const int nbx = N / TN;                 // 16
  const int cx = nbx >> 1;                // 8
  const int lin = blockIdx.x;
  const int xcd = lin & 7, wi = lin >> 3;
  const int bxi = (xcd & 1) * cx + wi % cx;
  const int byi = (xcd >> 1) * 8 + wi / cx;
  const int m0 = byi * 128, n0 = bxi * TN;

  auto stage = [&](int k0, int p) {
    __bf16* Ad = As + p * (128 * 32);
    __bf16* Bd = Bs + p * (TN * 32);
#pragma unroll
    for (int i = 0; i < 2; i++) {
      int tt = i * 256 + t;
      int row = tt >> 2, ch = tt & 3;
      int chs = ch ^ ((row >> 1) & 3);
      async16(A + (size_t)(m0 + row) * K + k0 + chs * 8, Ad + tt * 8);
    }
    {
      int tt = t;
      int row = tt >> 2, ch = tt & 3;
      int chs = ch ^ ((row >> 1) & 3);
      async16(BT + (size_t)(n0 + row) * K + k0 + chs * 8, Bd + tt * 8);
    }
  };

  const f32x4 zero4 = {0.f, 0.f, 0.f, 0.f};
  f32x4 acc[4][2];
#pragma unroll
  for (int i = 0; i < 4; i++)
#pragma unroll
    for (int j = 0; j < 2; j++) acc[i][j] = zero4;

  stage(0, 0);
  const int NIT = K / 32;
  for (int it = 0; it < NIT; it++) {
    __syncthreads();
    if (it + 1 < NIT) stage((it + 1) * 32, (it + 1) & 1);
    const __bf16* Asb = As + (it & 1) * (128 * 32);
    const __bf16* Bsb = Bs + (it & 1) * (TN * 32);
    bf16x8 af[4], bfr[2];
#pragma unroll
    for (int x = 0; x < 4; x++)
      af[x] = *(const bf16x8*)(Asb + (wm + x * 16 + ln) * 32 + sw8);
#pragma unroll
    for (int x = 0; x < 2; x++)
      bfr[x] = *(const bf16x8*)(Bsb + (wn + x * 16 + ln) * 32 + sw8);
#pragma unroll
    for (int mt = 0; mt < 4; mt++)
#pragma unroll
      for (int nt = 0; nt < 2; nt++)
        acc[mt][nt] = MFMA16(af[mt], bfr[nt], acc[mt][nt]);
  }
#pragma unroll
  for (int nt = 0; nt < 2; nt++) {
    int col = n0 + wn + nt * 16 + ln;
    float bv = bias[col];
#pragma unroll
    for (int mt = 0; mt < 4; mt++) {
#pragma unroll
      for (int r = 0; r < 4; r++) {
        int row = m0 + wm + mt * 16 + quad * 4 + r;
        Cout[(size_t)row * N + col] = acc[mt][nt][r] + bv;
      }
    }
  }
}

// ---------------- fused flash attention: static-max, register-P, MFMA row-sums ----
// R4: s_setprio(1) around MFMA clusters (T5) — verified 45.5 -> 43.5 us.
__global__ __launch_bounds__(512, 4) void k_attn(const __bf16* __restrict__ qkv,
                                                 const __bf16* __restrict__ vt,
                                                 __bf16* __restrict__ aout) {
  __shared__ __align__(16) __bf16 smem[32768];   // 64 KB: K dbuf 2x16K, V dbuf 2x16K
  const int t = threadIdx.x;           // 0..511
  const int lane = t & 63, wv = t >> 6;
  const int ln = lane & 15, quad = lane >> 4;
  const int sw8 = (quad ^ ((ln >> 1) & 3)) * 8;

  int gid = blockIdx.x;
  int slot = gid & 7, j = gid >> 3;
  int bh = slot * 4 + (j >> 4);     // 4 (b,h) pairs per XCD slot -> K/V pinned in XCD L2
  int qt0 = j & 15;
  const int b = bh >> 4, h = bh & 15;
  const int q0 = qt0 * 128;

  const __bf16* qbase = qkv + (size_t)b * SEQ * NQKV + h * 192;
  const __bf16* kbase = qbase + 64;
  const __bf16* vbase = vt + (size_t)bh * 64 * SEQ;

  // prologue: stage K(0), V(0) into parity-0 buffers (source-chunk swizzled)
#pragma unroll
  for (int i = 0; i < 2; i++) {
    int tt = i * 512 + t;
    int hh = tt >> 9, row = (tt >> 2) & 127, ch = tt & 3;
    int chs = ch ^ ((row >> 1) & 3);
    async16(kbase + (size_t)row * NQKV + hh * 32 + chs * 8, smem + tt * 8);
  }
#pragma unroll
  for (int i = 0; i < 2; i++) {
    int tt = i * 512 + t;
    int c = tt >> 8, d = (tt >> 2) & 63, w = tt & 3;
    int ws = w ^ ((d >> 1) & 3);
    async16(vbase + (size_t)d * SEQ + c * 32 + ws * 8, smem + 16384 + tt * 8);
  }

  // Q fragments (pre-scaled by CE): wave's 16 q rows, B-operand layout
  bf16x8 qf[2];
#pragma unroll
  for (int dc = 0; dc < 2; dc++)
    qf[dc] = *(const bf16x8*)(qbase + (size_t)(q0 + wv * 16 + ln) * NQKV + dc * 32 + quad * 8);

  union { unsigned u[4]; bf16x8 v; } ones;
  ones.u[0] = ones.u[1] = ones.u[2] = ones.u[3] = 0x3F803F80u;   // bf16 1.0 x8

  const f32x4 zero4 = {0.f, 0.f, 0.f, 0.f};
  f32x4 O[4];
  f32x4 Ol = zero4;                 // row-sums (l) via ones-MFMA, row-layout
#pragma unroll
  for (int dt = 0; dt < 4; dt++) O[dt] = zero4;

  for (int it = 0; it < SEQ / 128; it++) {
    __syncthreads();   // K(it)/V(it) landed; (it-1)'s buffers fully consumed
    const __bf16* Ks = smem + (it & 1) * 8192;
    const __bf16* Vs = smem + 16384 + (it & 1) * 8192;
    if (it + 1 < SEQ / 128) {   // prefetch next tile; flies over this tile's compute
      __bf16* Kd = smem + ((it + 1) & 1) * 8192;
      __bf16* Vd = smem + 16384 + ((it + 1) & 1) * 8192;
      const __bf16* kn = kbase + (size_t)(it + 1) * 128 * NQKV;
      const __bf16* vn = vbase + (it + 1) * 128;
#pragma unroll
      for (int i = 0; i < 2; i++) {
        int tt = i * 512 + t;
        int hh = tt >> 9, row = (tt >> 2) & 127, ch = tt & 3;
        int chs = ch ^ ((row >> 1) & 3);
        async16(kn + (size_t)row * NQKV + hh * 32 + chs * 8, Kd + tt * 8);
      }
#pragma unroll
      for (int i = 0; i < 2; i++) {
        int tt = i * 512 + t;
        int c = tt >> 8, d = (tt >> 2) & 63, w = tt & 3;
        int ws = w ^ ((d >> 1) & 3);
        async16(vn + (size_t)d * SEQ + c * 32 + ws * 8, Vd + tt * 8);
      }
    }

    // S^T = K * Q^T per 16-row blk; P = exp2(S^T) packed to bf16 immediately
    unsigned Pp[8][2];
#pragma unroll
    for (int blk = 0; blk < 8; blk++) {
      bf16x8 kf0 = *(const bf16x8*)(Ks +        (blk * 16 + ln) * 32 + sw8);
      bf16x8 kf1 = *(const bf16x8*)(Ks + 4096 + (blk * 16 + ln) * 32 + sw8);
      __builtin_amdgcn_s_setprio(1);
      f32x4 s = MFMA16(kf0, qf[0], zero4);
      s = MFMA16(kf1, qf[1], s);
      __builtin_amdgcn_s_setprio(0);
      Pp[blk][0] = pk2(fexp2(s[0]), fexp2(s[1]));
      Pp[blk][1] = pk2(fexp2(s[2]), fexp2(s[3]));
    }
    // O += P*V; Ol += P*1 (row-sums) — all on the MFMA pipe
#pragma unroll
    for (int kc = 0; kc < 4; kc++) {
      union { bf16x8 v; unsigned u[4]; } pf;
      pf.u[0] = Pp[kc][0]; pf.u[1] = Pp[kc][1];
      pf.u[2] = Pp[kc + 4][0]; pf.u[3] = Pp[kc + 4][1];
      __builtin_amdgcn_s_setprio(1);
      Ol = MFMA16(pf.v, ones.v, Ol);
#pragma unroll
      for (int dt = 0; dt < 4; dt++) {
        bf16x8 vf = *(const bf16x8*)(Vs + kc * 2048 + (dt * 16 + ln) * 32 + sw8);
        O[dt] = MFMA16(pf.v, vf, O[dt]);
      }
      __builtin_amdgcn_s_setprio(0);
    }
  }

  // epilogue: Ol[r] = l for q-row quad*4+r (same row-layout as O) -> no shuffles.
  __bf16* stage = smem + wv * 1024;   // wave-private 16x64
#pragma unroll
  for (int r = 0; r < 4; r++) {
    float ir = 1.0f / Ol[r];
#pragma unroll
    for (int dt = 0; dt < 4; dt++)
      stage[(quad * 4 + r) * 64 + dt * 16 + ln] = f2bf(O[dt][r] * ir);
  }
  __bf16* obase = aout + (size_t)(b * SEQ + q0 + wv * 16) * HIDDEN + h * 64;
#pragma unroll
  for (int i = 0; i < 2; i++) {
    int tt = i * 64 + lane; int row = tt >> 3, ch = tt & 7;
    *(bf16x8*)(obase + (size_t)row * HIDDEN + ch * 8) = *(const bf16x8*)(stage + row * 64 + ch * 8);
  }
}

extern "C" void kernel_launch(void* const* d_in, const int* in_sizes, int n_in,
                              void* d_out, int out_size, void* d_ws, size_t ws_size,
                              hipStream_t stream) {
  const float* x     = (const float*)d_in[0];
  const float* qkv_w = (const float*)d_in[1];
  const float* qkv_b = (const float*)d_in[2];
  const float* out_w = (const float*)d_in[3];
  const float* out_b = (const float*)d_in[4];

  char* ws = (char*)d_ws;
  __bf16* xb   = (__bf16*)(ws);                       // 4096*1024*2   =  8,388,608
  __bf16* wqkT = (__bf16*)(ws + 8388608);             // 3072*1024*2   =  6,291,456
  __bf16* woT  = (__bf16*)(ws + 14680064);            // 1024*1024*2   =  2,097,152
  __bf16* qkv  = (__bf16*)(ws + 16777216);            // 4096*3072*2   = 25,165,824 (V cols unused)
  __bf16* vt   = (__bf16*)(ws + 41943040);            // 32*64*2048*2  =  8,388,608
  __bf16* aout = (__bf16*)(ws + 50331648);            // 4096*1024*2   =  8,388,608

  k_prep<<<5120, 256, 0, stream>>>(x, xb, qkv_w, wqkT, out_w, woT);
  k_qkv<<<256, 512, 0, stream>>>(xb, wqkT, qkv_b, qkv, vt);
  k_attn<<<512, 512, 0, stream>>>(qkv, vt, aout);
  k_gemm_out<<<512, 256, 0, stream>>>(aout, woT, out_b, (float*)d_out, MTOT, HIDDEN, HIDDEN);
}

// Round 10
// 172.369 us; speedup vs baseline: 1.0913x; 1.0294x over previous
//
#include <hip/hip_runtime.h>
#include <hip/hip_bf16.h>
#include <cstdint>
#include <cstddef>

typedef float  f32x4  __attribute__((ext_vector_type(4)));
typedef __bf16 bf16x8 __attribute__((ext_vector_type(8)));
typedef __bf16 bf16x4 __attribute__((ext_vector_type(4)));

#define HIDDEN 1024
#define SEQ    2048
#define BATCH  2
#define NQKV   3072
#define MTOT   4096

__device__ __forceinline__ __bf16 f2bf(float f) {
  unsigned u = __builtin_bit_cast(unsigned, f);
  u += 0x7FFFu + ((u >> 16) & 1u);          // round-to-nearest-even
  unsigned short s = (unsigned short)(u >> 16);
  return __builtin_bit_cast(__bf16, s);
}

// pack two f32 -> bf16x2 (round-half-up) in 3 VALU: 2 adds + 1 v_perm_b32
// R10: REVERTED from v_cvt_pk_bf16_f32 — that instruction truncates toward
// zero on gfx950; the downward bias in P drove absmax 2.5e-4 -> 1.3e-3 (R9
// correctness failure). pk2's round-half-up is what the passing baseline used.
__device__ __forceinline__ unsigned pk2(float a, float b) {
  unsigned ua = __builtin_bit_cast(unsigned, a) + 0x8000u;
  unsigned ub = __builtin_bit_cast(unsigned, b) + 0x8000u;
  return __builtin_amdgcn_perm(ub, ua, 0x07060302u);  // {hi16(ub), hi16(ua)}
}

__device__ __forceinline__ float fexp2(float x) {
#if __has_builtin(__builtin_amdgcn_exp2f)
  return __builtin_amdgcn_exp2f(x);   // bare v_exp_f32
#else
  return exp2f(x);
#endif
}

__device__ __forceinline__ void async16(const void* g, void* l) {
  __builtin_amdgcn_global_load_lds((__attribute__((address_space(1))) void*)(g),
                                   (__attribute__((address_space(3))) void*)(l),
                                   16, 0, 0);
}

#define MFMA16(a, b, c) __builtin_amdgcn_mfma_f32_16x16x32_bf16((a), (b), (c), 0, 0, 0)

// ---------------- prep: x->bf16 convert + both weight transposes (one launch) ----
__global__ __launch_bounds__(256) void k_prep(const float* __restrict__ x,
                                              __bf16* __restrict__ xb,
                                              const float* __restrict__ qkv_w,
                                              __bf16* __restrict__ wqkT,
                                              const float* __restrict__ out_w,
                                              __bf16* __restrict__ woT) {
  __shared__ float tile[64][65];
  const int bid = blockIdx.x, t = threadIdx.x;
  if (bid < 4096) {
    int i = bid * 256 + t;
    float4 v = ((const float4*)x)[i];
    bf16x4 o;
    o[0] = f2bf(v.x); o[1] = f2bf(v.y); o[2] = f2bf(v.z); o[3] = f2bf(v.w);
    ((bf16x4*)xb)[i] = o;
    return;
  }
  const float* W; __bf16* WT; int N, bx, by;
  if (bid < 4864) { int g = bid - 4096; W = qkv_w; WT = wqkT; N = NQKV;  bx = g % 48; by = g / 48; }
  else            { int g = bid - 4864; W = out_w; WT = woT;  N = HIDDEN; bx = g % 16; by = g / 16; }
  const int K = HIDDEN;
  int tx = t & 63, ty = t >> 6;
  int n0 = bx * 64, k0 = by * 64;
#pragma unroll
  for (int r = 0; r < 16; r++) {
    int row = r * 4 + ty;
    tile[row][tx] = W[(size_t)(k0 + row) * N + n0 + tx];
  }
  __syncthreads();
#pragma unroll
  for (int i2 = 0; i2 < 2; i2++) {
    int cc = i2 * 256 + t;
    int n = cc >> 3, ch = cc & 7;
    bf16x8 o;
#pragma unroll
    for (int j = 0; j < 8; j++) o[j] = f2bf(tile[ch * 8 + j][n]);
    *(bf16x8*)(WT + (size_t)(n0 + n) * K + k0 + ch * 8) = o;
  }
}

// ---------------- QKV GEMM: 256x192, BK=64, 4-phase counted schedule ------------
// R8 (verified): 8 waves (2M x 4N), per-wave 128x48, acc[8][3]; grid 256 = 1/CU,
// XCD-bijective 4bx x 8by. Phases (m-half x k-half), counted vmcnt(5)/tile,
// A halves bit-striped, B unsplit; chunk-XOR swizzle both sides.
__global__ __launch_bounds__(512, 2) void k_qkv(const __bf16* __restrict__ A,
                                                const __bf16* __restrict__ BT,
                                                const float* __restrict__ bias,
                                                __bf16* __restrict__ Cout,
                                                __bf16* __restrict__ vt) {
  const int K = HIDDEN;
  __shared__ __align__(16) __bf16 As[2][2][8192];   // [parity][half][128 striped rows x 64 k]
  __shared__ __align__(16) __bf16 Bs[2][12288];     // [parity][192 rows x 64 k]
  const int t = threadIdx.x;
  const int lane = t & 63, wv = t >> 6;
  const int ln = lane & 15, quad = lane >> 4;
  const int wm = (wv >> 2) * 128, wn = (wv & 3) * 48;

  const int lin = blockIdx.x;
  const int xcd = lin & 7, wi = lin >> 3;          // wi in [0,32)
  const int bxi = (xcd & 3) * 4 + (wi & 3);        // [0,16)
  const int byi = (xcd >> 2) * 8 + (wi >> 2);      // [0,16)
  const int m0 = byi * 256, n0 = bxi * 192;

  auto stA = [&](int kt, int h) {
    __bf16* dst = &As[kt & 1][h][0];
    const __bf16* src = A + (size_t)m0 * K + kt * 64;
#pragma unroll
    for (int i = 0; i < 2; i++) {
      int tt = i * 512 + t;
      int sr = tt >> 3, ch = tt & 7;
      int gr = (sr & 63) + ((sr >> 6) << 7) + h * 64;   // striped row
      async16(src + (size_t)gr * K + ((ch ^ (sr & 7)) * 8), dst + tt * 8);
    }
  };
  auto stB = [&](int kt) {
    __bf16* dst = &Bs[kt & 1][0];
    const __bf16* src = BT + (size_t)n0 * K + kt * 64;
#pragma unroll
    for (int i = 0; i < 3; i++) {
      int tt = i * 512 + t;
      int row = tt >> 3, ch = tt & 7;
      async16(src + (size_t)row * K + ((ch ^ (row & 7)) * 8), dst + tt * 8);
    }
  };

  const f32x4 zero4 = {0.f, 0.f, 0.f, 0.f};
  f32x4 acc[8][3];
#pragma unroll
  for (int i = 0; i < 8; i++)
#pragma unroll
    for (int j = 0; j < 3; j++) acc[i][j] = zero4;

  // prologue (FIFO: A(0,h0), B(0), A(0,h1), A(1,h0), B(1) = 12 loads)
  stA(0, 0); stB(0); stA(0, 1); stA(1, 0); stB(1);

  bf16x8 a0[4], a1[4], b0[3], b1[3];
  const int sra = ln + ((wv >> 2) << 6);        // in-half A row base (+ m*16)
  const int srb = (wv & 3) * 48 + ln;           // B row base (+ nt*16)
  const int swz = ln & 7;

  const int NT = K / 64;   // 16
  for (int kt = 0; kt < NT; kt++) {
    const int p = kt & 1;
    if (kt < NT - 1) asm volatile("s_waitcnt vmcnt(5)" ::: "memory");
    else             asm volatile("s_waitcnt vmcnt(0)" ::: "memory");
    __builtin_amdgcn_s_barrier();
    const __bf16* A0 = &As[p][0][0];
    const __bf16* A1 = &As[p][1][0];
    const __bf16* Bb = &Bs[p][0];
    // ---------------- P0: m-lo x k0-31
    {
#pragma unroll
      for (int m = 0; m < 4; m++)
        a0[m] = *(const bf16x8*)(A0 + (sra + m * 16) * 64 + ((quad ^ swz) * 8));
#pragma unroll
      for (int n = 0; n < 3; n++)
        b0[n] = *(const bf16x8*)(Bb + (srb + n * 16) * 64 + ((quad ^ swz) * 8));
      if (kt + 1 < NT) stA(kt + 1, 1);
      __builtin_amdgcn_s_barrier();
      asm volatile("s_waitcnt lgkmcnt(0)" ::: "memory");
      __builtin_amdgcn_sched_barrier(0);
      __builtin_amdgcn_s_setprio(1);
#pragma unroll
      for (int m = 0; m < 4; m++)
#pragma unroll
        for (int n = 0; n < 3; n++)
          acc[m][n] = MFMA16(a0[m], b0[n], acc[m][n]);
      __builtin_amdgcn_s_setprio(0);
      __builtin_amdgcn_s_barrier();
    }
    // ---------------- P1: m-lo x k32-63
    {
#pragma unroll
      for (int m = 0; m < 4; m++)
        a1[m] = *(const bf16x8*)(A0 + (sra + m * 16) * 64 + (((4 + quad) ^ swz) * 8));
#pragma unroll
      for (int n = 0; n < 3; n++)
        b1[n] = *(const bf16x8*)(Bb + (srb + n * 16) * 64 + (((4 + quad) ^ swz) * 8));
      __builtin_amdgcn_s_barrier();
      asm volatile("s_waitcnt lgkmcnt(0)" ::: "memory");
      __builtin_amdgcn_sched_barrier(0);
      __builtin_amdgcn_s_setprio(1);
#pragma unroll
      for (int m = 0; m < 4; m++)
#pragma unroll
        for (int n = 0; n < 3; n++)
          acc[m][n] = MFMA16(a1[m], b1[n], acc[m][n]);
      __builtin_amdgcn_s_setprio(0);
      __builtin_amdgcn_s_barrier();
    }
    // ---------------- P2: m-hi x k0-31 (b0 still live)
    {
#pragma unroll
      for (int m = 0; m < 4; m++)
        a0[m] = *(const bf16x8*)(A1 + (sra + m * 16) * 64 + ((quad ^ swz) * 8));
      if (kt + 2 < NT) stA(kt + 2, 0);
      __builtin_amdgcn_s_barrier();
      asm volatile("s_waitcnt lgkmcnt(0)" ::: "memory");
      __builtin_amdgcn_sched_barrier(0);
      __builtin_amdgcn_s_setprio(1);
#pragma unroll
      for (int m = 0; m < 4; m++)
#pragma unroll
        for (int n = 0; n < 3; n++)
          acc[4 + m][n] = MFMA16(a0[m], b0[n], acc[4 + m][n]);
      __builtin_amdgcn_s_setprio(0);
      __builtin_amdgcn_s_barrier();
    }
    // ---------------- P3: m-hi x k32-63 (b1 still live)
    {
#pragma unroll
      for (int m = 0; m < 4; m++)
        a1[m] = *(const bf16x8*)(A1 + (sra + m * 16) * 64 + (((4 + quad) ^ swz) * 8));
      if (kt + 2 < NT) stB(kt + 2);
      __builtin_amdgcn_s_barrier();
      asm volatile("s_waitcnt lgkmcnt(0)" ::: "memory");
      __builtin_amdgcn_sched_barrier(0);
      __builtin_amdgcn_s_setprio(1);
#pragma unroll
      for (int m = 0; m < 4; m++)
#pragma unroll
        for (int n = 0; n < 3; n++)
          acc[4 + m][n] = MFMA16(a1[m], b1[n], acc[4 + m][n]);
      __builtin_amdgcn_s_setprio(0);
      // closing barrier is the next kt's top {vmcnt; s_barrier}
    }
  }

  const float CE = 0.125f * 1.44269504089f;
#pragma unroll
  for (int nt = 0; nt < 3; nt++) {
    int g = n0 + wn + nt * 16;      // lane-uniform 16-col group base
    int col = g + ln;
    float bv = bias[col];
    int off = g % 192;
    if (off < 128) {
      float scl = (off < 64) ? CE : 1.0f;    // pre-scale Q by CE
#pragma unroll
      for (int mt = 0; mt < 8; mt++) {
#pragma unroll
        for (int r = 0; r < 4; r++) {
          int row = m0 + wm + mt * 16 + quad * 4 + r;
          Cout[(size_t)row * NQKV + col] = f2bf((acc[mt][nt][r] + bv) * scl);
        }
      }
    } else {
      // V path: vt[bh][d][sblk*128 + p], p = permuted in-block position
      int hg = g / 192;
      int d  = off - 128 + ln;
#pragma unroll
      for (int mt = 0; mt < 8; mt++) {
        int rowb = m0 + wm + mt * 16;        // + quad*4 + r
        int bb = rowb >> 11;
        int s  = rowb & 2047;
        int sblk = s >> 7;
        int blk  = (s >> 4) & 7;             // (s%128)/16
        int pp = (blk & 3) * 32 + quad * 8 + ((blk >> 2) << 2);
        uint2 o;
        o.x = pk2(acc[mt][nt][0] + bv, acc[mt][nt][1] + bv);
        o.y = pk2(acc[mt][nt][2] + bv, acc[mt][nt][3] + bv);
        *(uint2*)(vt + ((size_t)((bb * 16 + hg) * 64 + d)) * SEQ + sblk * 128 + pp) = o;
      }
    }
  }
}

// ---------------- out GEMM: 128x128, BK=64, 2-phase counted (R8-skeleton port) --
// R9 design, re-audited clean (stripe map, bijectivity, vmcnt FIFO, liveness,
// XOR involution). 8 waves; A bit5-striped halves; counted vmcnt(3)/tile;
// grid 256 = 1/CU, XCD-bijective.
__global__ __launch_bounds__(512, 2) void k_out(const __bf16* __restrict__ A,
                                                const __bf16* __restrict__ BT,
                                                const float* __restrict__ bias,
                                                float* __restrict__ Cout) {
  const int K = HIDDEN, N = HIDDEN;
  __shared__ __align__(16) __bf16 As[2][2][4096];   // [parity][half][64 striped rows x 64 k]
  __shared__ __align__(16) __bf16 Bs[2][8192];      // [parity][128 rows x 64 k]
  const int t = threadIdx.x;
  const int lane = t & 63, wv = t >> 6;
  const int ln = lane & 15, quad = lane >> 4;
  const int wm = (wv >> 2) * 64, wn = (wv & 3) * 32;

  const int lin = blockIdx.x;
  const int xcd = lin & 7, wi = lin >> 3;          // wi in [0,32)
  const int bxi = (xcd & 1) * 4 + (wi & 3);        // [0,8)
  const int byi = (xcd >> 1) * 8 + (wi >> 2);      // [0,32)
  const int m0 = byi * 128, n0 = bxi * 128;

  auto stA = [&](int kt, int h) {                   // 1 load/thread
    __bf16* dst = &As[kt & 1][h][0];
    const __bf16* src = A + (size_t)m0 * K + kt * 64;
    int sr = t >> 3, ch = t & 7;
    int gr = (sr & 31) + ((sr >> 5) << 6) + h * 32;   // striped row
    async16(src + (size_t)gr * K + ((ch ^ (sr & 7)) * 8), dst + t * 8);
  };
  auto stB = [&](int kt) {                          // 2 loads/thread
    __bf16* dst = &Bs[kt & 1][0];
    const __bf16* src = BT + (size_t)n0 * K + kt * 64;
#pragma unroll
    for (int i = 0; i < 2; i++) {
      int tt = i * 512 + t;
      int row = tt >> 3, ch = tt & 7;
      async16(src + (size_t)row * K + ((ch ^ (row & 7)) * 8), dst + tt * 8);
    }
  };

  const f32x4 zero4 = {0.f, 0.f, 0.f, 0.f};
  f32x4 acc[4][2];
#pragma unroll
  for (int i = 0; i < 4; i++)
#pragma unroll
    for (int j = 0; j < 2; j++) acc[i][j] = zero4;

  // prologue (FIFO: A(0,h0), B(0), A(0,h1), A(1,h0), B(1) = 7 loads)
  stA(0, 0); stB(0); stA(0, 1); stA(1, 0); stB(1);

  bf16x8 af[2][2], bfr[2][2];
  const int sra = ln + ((wv >> 2) << 5);        // in-half A row base (+ m*16)
  const int srb = wn + ln;                      // B row base (+ n*16)
  const int swz = ln & 7;

  const int NT = K / 64;   // 16
  for (int kt = 0; kt < NT; kt++) {
    const int p = kt & 1;
    if (kt < NT - 1) asm volatile("s_waitcnt vmcnt(3)" ::: "memory");
    else             asm volatile("s_waitcnt vmcnt(0)" ::: "memory");
    __builtin_amdgcn_s_barrier();
    const __bf16* A0 = &As[p][0][0];
    const __bf16* A1 = &As[p][1][0];
    const __bf16* Bb = &Bs[p][0];
    // ---------------- P0: m-stripe0, full k; b loaded for both phases
    {
#pragma unroll
      for (int m = 0; m < 2; m++)
#pragma unroll
        for (int kk = 0; kk < 2; kk++)
          af[m][kk] = *(const bf16x8*)(A0 + (sra + m * 16) * 64 + (((kk * 4 + quad) ^ swz) * 8));
#pragma unroll
      for (int n = 0; n < 2; n++)
#pragma unroll
        for (int kk = 0; kk < 2; kk++)
          bfr[n][kk] = *(const bf16x8*)(Bb + (srb + n * 16) * 64 + (((kk * 4 + quad) ^ swz) * 8));
      if (kt + 1 < NT) stA(kt + 1, 1);
      __builtin_amdgcn_s_barrier();
      asm volatile("s_waitcnt lgkmcnt(0)" ::: "memory");
      __builtin_amdgcn_sched_barrier(0);
      __builtin_amdgcn_s_setprio(1);
#pragma unroll
      for (int m = 0; m < 2; m++)
#pragma unroll
        for (int n = 0; n < 2; n++) {
          acc[m][n] = MFMA16(af[m][0], bfr[n][0], acc[m][n]);
          acc[m][n] = MFMA16(af[m][1], bfr[n][1], acc[m][n]);
        }
      __builtin_amdgcn_s_setprio(0);
      __builtin_amdgcn_s_barrier();
    }
    // ---------------- P1: m-stripe1, full k (b reused)
    {
#pragma unroll
      for (int m = 0; m < 2; m++)
#pragma unroll
        for (int kk = 0; kk < 2; kk++)
          af[m][kk] = *(const bf16x8*)(A1 + (sra + m * 16) * 64 + (((kk * 4 + quad) ^ swz) * 8));
      if (kt + 2 < NT) { stA(kt + 2, 0); stB(kt + 2); }
      __builtin_amdgcn_s_barrier();
      asm volatile("s_waitcnt lgkmcnt(0)" ::: "memory");
      __builtin_amdgcn_sched_barrier(0);
      __builtin_amdgcn_s_setprio(1);
#pragma unroll
      for (int m = 0; m < 2; m++)
#pragma unroll
        for (int n = 0; n < 2; n++) {
          acc[2 + m][n] = MFMA16(af[m][0], bfr[n][0], acc[2 + m][n]);
          acc[2 + m][n] = MFMA16(af[m][1], bfr[n][1], acc[2 + m][n]);
        }
      __builtin_amdgcn_s_setprio(0);
      // closing barrier is the next kt's top {vmcnt; s_barrier}
    }
  }

  // epilogue: row = m0 + wm + h*32 + m*16 + quad*4 + r; col = n0 + wn + n*16 + ln
#pragma unroll
  for (int h = 0; h < 2; h++)
#pragma unroll
    for (int n = 0; n < 2; n++) {
      int col = n0 + wn + n * 16 + ln;
      float bv = bias[col];
#pragma unroll
      for (int m = 0; m < 2; m++)
#pragma unroll
        for (int r = 0; r < 4; r++) {
          int row = m0 + wm + h * 32 + m * 16 + quad * 4 + r;
          Cout[(size_t)row * N + col] = acc[h * 2 + m][n][r] + bv;
        }
    }
}

// ---------------- fused flash attention: static-max, register-P, MFMA row-sums ----
// R4: s_setprio(1) around MFMA clusters (T5) — verified 45.5 -> 43.5 us.
// R10: P-pack back to pk2 (round-half-up) — cvt_pk truncates on gfx950 (R9 fail).
__global__ __launch_bounds__(512, 4) void k_attn(const __bf16* __restrict__ qkv,
                                                 const __bf16* __restrict__ vt,
                                                 __bf16* __restrict__ aout) {
  __shared__ __align__(16) __bf16 smem[32768];   // 64 KB: K dbuf 2x16K, V dbuf 2x16K
  const int t = threadIdx.x;           // 0..511
  const int lane = t & 63, wv = t >> 6;
  const int ln = lane & 15, quad = lane >> 4;
  const int sw8 = (quad ^ ((ln >> 1) & 3)) * 8;

  int gid = blockIdx.x;
  int slot = gid & 7, j = gid >> 3;
  int bh = slot * 4 + (j >> 4);     // 4 (b,h) pairs per XCD slot -> K/V pinned in XCD L2
  int qt0 = j & 15;
  const int b = bh >> 4, h = bh & 15;
  const int q0 = qt0 * 128;

  const __bf16* qbase = qkv + (size_t)b * SEQ * NQKV + h * 192;
  const __bf16* kbase = qbase + 64;
  const __bf16* vbase = vt + (size_t)bh * 64 * SEQ;

  // prologue: stage K(0), V(0) into parity-0 buffers (source-chunk swizzled)
#pragma unroll
  for (int i = 0; i < 2; i++) {
    int tt = i * 512 + t;
    int hh = tt >> 9, row = (tt >> 2) & 127, ch = tt & 3;
    int chs = ch ^ ((row >> 1) & 3);
    async16(kbase + (size_t)row * NQKV + hh * 32 + chs * 8, smem + tt * 8);
  }
#pragma unroll
  for (int i = 0; i < 2; i++) {
    int tt = i * 512 + t;
    int c = tt >> 8, d = (tt >> 2) & 63, w = tt & 3;
    int ws = w ^ ((d >> 1) & 3);
    async16(vbase + (size_t)d * SEQ + c * 32 + ws * 8, smem + 16384 + tt * 8);
  }

  // Q fragments (pre-scaled by CE): wave's 16 q rows, B-operand layout
  bf16x8 qf[2];
#pragma unroll
  for (int dc = 0; dc < 2; dc++)
    qf[dc] = *(const bf16x8*)(qbase + (size_t)(q0 + wv * 16 + ln) * NQKV + dc * 32 + quad * 8);

  union { unsigned u[4]; bf16x8 v; } ones;
  ones.u[0] = ones.u[1] = ones.u[2] = ones.u[3] = 0x3F803F80u;   // bf16 1.0 x8

  const f32x4 zero4 = {0.f, 0.f, 0.f, 0.f};
  f32x4 O[4];
  f32x4 Ol = zero4;                 // row-sums (l) via ones-MFMA, row-layout
#pragma unroll
  for (int dt = 0; dt < 4; dt++) O[dt] = zero4;

  for (int it = 0; it < SEQ / 128; it++) {
    __syncthreads();   // K(it)/V(it) landed; (it-1)'s buffers fully consumed
    const __bf16* Ks = smem + (it & 1) * 8192;
    const __bf16* Vs = smem + 16384 + (it & 1) * 8192;
    if (it + 1 < SEQ / 128) {   // prefetch next tile; flies over this tile's compute
      __bf16* Kd = smem + ((it + 1) & 1) * 8192;
      __bf16* Vd = smem + 16384 + ((it + 1) & 1) * 8192;
      const __bf16* kn = kbase + (size_t)(it + 1) * 128 * NQKV;
      const __bf16* vn = vbase + (it + 1) * 128;
#pragma unroll
      for (int i = 0; i < 2; i++) {
        int tt = i * 512 + t;
        int hh = tt >> 9, row = (tt >> 2) & 127, ch = tt & 3;
        int chs = ch ^ ((row >> 1) & 3);
        async16(kn + (size_t)row * NQKV + hh * 32 + chs * 8, Kd + tt * 8);
      }
#pragma unroll
      for (int i = 0; i < 2; i++) {
        int tt = i * 512 + t;
        int c = tt >> 8, d = (tt >> 2) & 63, w = tt & 3;
        int ws = w ^ ((d >> 1) & 3);
        async16(vn + (size_t)d * SEQ + c * 32 + ws * 8, Vd + tt * 8);
      }
    }

    // S^T = K * Q^T per 16-row blk; P = exp2(S^T) packed to bf16 immediately
    unsigned Pp[8][2];
#pragma unroll
    for (int blk = 0; blk < 8; blk++) {
      bf16x8 kf0 = *(const bf16x8*)(Ks +        (blk * 16 + ln) * 32 + sw8);
      bf16x8 kf1 = *(const bf16x8*)(Ks + 4096 + (blk * 16 + ln) * 32 + sw8);
      __builtin_amdgcn_s_setprio(1);
      f32x4 s = MFMA16(kf0, qf[0], zero4);
      s = MFMA16(kf1, qf[1], s);
      __builtin_amdgcn_s_setprio(0);
      Pp[blk][0] = pk2(fexp2(s[0]), fexp2(s[1]));
      Pp[blk][1] = pk2(fexp2(s[2]), fexp2(s[3]));
    }
    // O += P*V; Ol += P*1 (row-sums) — all on the MFMA pipe
#pragma unroll
    for (int kc = 0; kc < 4; kc++) {
      union { bf16x8 v; unsigned u[4]; } pf;
      pf.u[0] = Pp[kc][0]; pf.u[1] = Pp[kc][1];
      pf.u[2] = Pp[kc + 4][0]; pf.u[3] = Pp[kc + 4][1];
      __builtin_amdgcn_s_setprio(1);
      Ol = MFMA16(pf.v, ones.v, Ol);
#pragma unroll
      for (int dt = 0; dt < 4; dt++) {
        bf16x8 vf = *(const bf16x8*)(Vs + kc * 2048 + (dt * 16 + ln) * 32 + sw8);
        O[dt] = MFMA16(pf.v, vf, O[dt]);
      }
      __builtin_amdgcn_s_setprio(0);
    }
  }

  // epilogue: Ol[r] = l for q-row quad*4+r (same row-layout as O) -> no shuffles.
  __bf16* stage = smem + wv * 1024;   // wave-private 16x64
#pragma unroll
  for (int r = 0; r < 4; r++) {
    float ir = 1.0f / Ol[r];
#pragma unroll
    for (int dt = 0; dt < 4; dt++)
      stage[(quad * 4 + r) * 64 + dt * 16 + ln] = f2bf(O[dt][r] * ir);
  }
  __bf16* obase = aout + (size_t)(b * SEQ + q0 + wv * 16) * HIDDEN + h * 64;
#pragma unroll
  for (int i = 0; i < 2; i++) {
    int tt = i * 64 + lane; int row = tt >> 3, ch = tt & 7;
    *(bf16x8*)(obase + (size_t)row * HIDDEN + ch * 8) = *(const bf16x8*)(stage + row * 64 + ch * 8);
  }
}

extern "C" void kernel_launch(void* const* d_in, const int* in_sizes, int n_in,
                              void* d_out, int out_size, void* d_ws, size_t ws_size,
                              hipStream_t stream) {
  const float* x     = (const float*)d_in[0];
  const float* qkv_w = (const float*)d_in[1];
  const float* qkv_b = (const float*)d_in[2];
  const float* out_w = (const float*)d_in[3];
  const float* out_b = (const float*)d_in[4];

  char* ws = (char*)d_ws;
  __bf16* xb   = (__bf16*)(ws);                       // 4096*1024*2   =  8,388,608
  __bf16* wqkT = (__bf16*)(ws + 8388608);             // 3072*1024*2   =  6,291,456
  __bf16* woT  = (__bf16*)(ws + 14680064);            // 1024*1024*2   =  2,097,152
  __bf16* qkv  = (__bf16*)(ws + 16777216);            // 4096*3072*2   = 25,165,824 (V cols unused)
  __bf16* vt   = (__bf16*)(ws + 41943040);            // 32*64*2048*2  =  8,388,608
  __bf16* aout = (__bf16*)(ws + 50331648);            // 4096*1024*2   =  8,388,608

  k_prep<<<5120, 256, 0, stream>>>(x, xb, qkv_w, wqkT, out_w, woT);
  k_qkv<<<256, 512, 0, stream>>>(xb, wqkT, qkv_b, qkv, vt);
  k_attn<<<512, 512, 0, stream>>>(qkv, vt, aout);
  k_out<<<256, 512, 0, stream>>>(aout, woT, out_b, (float*)d_out);
}